// Round 1
// baseline (2248.265 us; speedup 1.0000x reference)
//
#include <hip/hip_runtime.h>
#include <math.h>

#define MN 1537          // M_NODES
#define NFFT 4096
#define CW 0.06283185307179587f   // 2*pi*h
#define W4096 1.5339807878856412e-3f // 2*pi/4096

__device__ inline float2 cmulf(float2 a, float2 b) {
    return make_float2(a.x*b.x - a.y*b.y, a.x*b.y + a.y*b.x);
}

__device__ inline float ws_at(int k) {
    float xi = 0.01f * (float)(k - 768);
    float t  = 0.31415926535897931f * xi;      // pi*ell*xi, ell=0.1
    float S  = 0.25066282746310002f * expf(-2.0f * t * t); // sqrt(2pi)*ell
    return sqrtf(0.01f * S);
}

// ---------------- FFT: DIF forward (natural -> bitrev), DIT inverse (bitrev -> natural)
__device__ void fft_dif(float2* buf, int tid, int nthr) {
    for (int s = 11; s >= 0; --s) {
        int half = 1 << s;
        for (int t = tid; t < 2048; t += nthr) {
            int pos = t & (half - 1);
            int i0 = ((t >> s) << (s + 1)) + pos;
            int i1 = i0 + half;
            float2 a = buf[i0], b = buf[i1];
            float ang = -W4096 * (float)(pos << (11 - s));
            float sn, cs; __sincosf(ang, &sn, &cs);
            buf[i0] = make_float2(a.x + b.x, a.y + b.y);
            float2 d = make_float2(a.x - b.x, a.y - b.y);
            buf[i1] = cmulf(d, make_float2(cs, sn));
        }
        __syncthreads();
    }
}

__device__ void fft_dit_inv(float2* buf, int tid, int nthr) {
    for (int s = 0; s <= 11; ++s) {
        int half = 1 << s;
        for (int t = tid; t < 2048; t += nthr) {
            int pos = t & (half - 1);
            int i0 = ((t >> s) << (s + 1)) + pos;
            int i1 = i0 + half;
            float ang = W4096 * (float)(pos << (11 - s));
            float sn, cs; __sincosf(ang, &sn, &cs);
            float2 a = buf[i0];
            float2 b = cmulf(buf[i1], make_float2(cs, sn));
            buf[i0] = make_float2(a.x + b.x, a.y + b.y);
            buf[i1] = make_float2(a.x - b.x, a.y - b.y);
        }
        __syncthreads();
    }
}

// ---------------- block-wide sum reduce (1024 threads = 16 waves), result to all
__device__ float block_reduce(float v, volatile float* scratch) {
    int lane = threadIdx.x & 63;
    int wid  = threadIdx.x >> 6;
    #pragma unroll
    for (int off = 32; off > 0; off >>= 1) v += __shfl_down(v, off, 64);
    if (lane == 0) scratch[wid] = v;
    __syncthreads();
    if (wid == 0) {
        float s = (lane < (int)(blockDim.x >> 6)) ? scratch[lane] : 0.0f;
        #pragma unroll
        for (int off = 8; off > 0; off >>= 1) s += __shfl_down(s, off, 64);
        if (lane == 0) scratch[16] = s;
    }
    __syncthreads();
    return scratch[16];
}

// ---------------- K1: vfull[p] = sum_n exp(i*2pi*h*x_n*p), p = idx-1536
__global__ void k_vfull(const float* __restrict__ x, float2* __restrict__ d_v) {
    int pi = blockIdx.x * 256 + threadIdx.x;
    if (pi >= 3073) return;
    float p = (float)(pi - 1536);
    int n0 = blockIdx.y * 1024;
    float sx = 0.f, sy = 0.f;
    for (int n = n0; n < n0 + 1024; ++n) {
        float ph = CW * (x[n] * p);
        float s, c; __sincosf(ph, &s, &c);
        sx += c; sy += s;
    }
    atomicAdd(&d_v[pi].x, sx);
    atomicAdd(&d_v[pi].y, sy);
}

// ---------------- K2: rhsraw[k] = sum_n exp(-i*2pi*h*x_n*(k-768)) * y_n
__global__ void k_fhy(const float* __restrict__ x, const float* __restrict__ y,
                      float2* __restrict__ d_rhs) {
    int k = blockIdx.x * 256 + threadIdx.x;
    if (k >= MN) return;
    float kk = (float)(k - 768);
    int n0 = blockIdx.y * 1024;
    float sx = 0.f, sy = 0.f;
    for (int n = n0; n < n0 + 1024; ++n) {
        float ph = CW * (x[n] * kk);
        float s, c; __sincosf(ph, &s, &c);
        sx += c * y[n]; sy -= s * y[n];
    }
    atomicAdd(&d_rhs[k].x, sx);
    atomicAdd(&d_rhs[k].y, sy);
}

// ---------------- K3: G = FFT4096(g), bit-reversed order, g[t mod 4096] = v_{-t}
__global__ __launch_bounds__(1024) void k_buildG(const float2* __restrict__ d_v,
                                                 float2* __restrict__ d_G) {
    __shared__ float2 buf[NFFT];
    int tid = threadIdx.x;
    for (int i = tid; i < NFFT; i += 1024) {
        float2 val = make_float2(0.f, 0.f);
        if (i == 0)            val = d_v[1536];
        else if (i <= 1536)    val = d_v[1536 - i];
        else if (i >= 2560)    val = d_v[5632 - i];   // v_{4096-i}
        buf[i] = val;
    }
    __syncthreads();
    fft_dif(buf, tid, 1024);
    for (int i = tid; i < NFFT; i += 1024) d_G[i] = buf[i];
}

// ---------------- K4: blocks 0..63 = Lanczos per probe; block 64 = CG
__global__ __launch_bounds__(1024) void k_solve(
    const float2* __restrict__ d_G, const float2* __restrict__ d_rhs,
    const float* __restrict__ d_z, float2* __restrict__ d_wb,
    float* __restrict__ d_al, float* __restrict__ d_be, float* __restrict__ d_nz2)
{
    __shared__ float2 fb[NFFT];
    __shared__ float2 va[MN];
    __shared__ float2 vb[MN];
    __shared__ float  lws[MN];
    __shared__ float  red[17];
    int tid = threadIdx.x;
    int b = blockIdx.x;
    for (int i = tid; i < MN; i += 1024) lws[i] = ws_at(i);
    __syncthreads();

    if (b < 64) {
        // ---------- Lanczos: va = q, vb = q_prev, v lives in fb[0:MN]
        float part = 0.f;
        for (int j = tid; j < MN; j += 1024) {
            float zv = d_z[b * MN + j];
            float s = (zv > 0.f) ? 1.f : ((zv < 0.f) ? -1.f : 0.f);
            va[j] = make_float2(s, 0.f);
            part += s * s;
        }
        __syncthreads();
        float nz2 = block_reduce(part, red);
        if (tid == 0) d_nz2[b] = nz2;
        float qs = 1.0f / sqrtf(nz2);
        for (int j = tid; j < MN; j += 1024) {
            float2 q = va[j];
            va[j] = make_float2(q.x * qs, q.y * qs);
            vb[j] = make_float2(0.f, 0.f);
        }
        __syncthreads();
        float beta_prev = 0.f;
        for (int step = 0; step < 50; ++step) {
            for (int i = tid; i < NFFT; i += 1024) {
                float2 val = make_float2(0.f, 0.f);
                if (i < MN) { float w = lws[i]; float2 q = va[i]; val = make_float2(w*q.x, w*q.y); }
                fb[i] = val;
            }
            __syncthreads();
            fft_dif(fb, tid, 1024);
            for (int i = tid; i < NFFT; i += 1024) fb[i] = cmulf(fb[i], d_G[i]);
            __syncthreads();
            fft_dit_inv(fb, tid, 1024);
            part = 0.f;
            for (int j = tid; j < MN; j += 1024) {
                float cf = lws[j] * (10.0f / 4096.0f); // (1/sigma^2) * (1/N)
                float2 q = va[j], qp = vb[j];
                float2 v = make_float2(q.x + cf*fb[j].x - beta_prev*qp.x,
                                       q.y + cf*fb[j].y - beta_prev*qp.y);
                fb[j] = v;
                part += q.x*v.x + q.y*v.y;
            }
            float alpha = block_reduce(part, red);
            part = 0.f;
            for (int j = tid; j < MN; j += 1024) {
                float2 q = va[j];
                float2 v = fb[j];
                v.x -= alpha*q.x; v.y -= alpha*q.y;
                fb[j] = v;
                part += v.x*v.x + v.y*v.y;
            }
            float nv = block_reduce(part, red);
            float beta = sqrtf(nv);
            if (tid == 0) { d_al[b*50 + step] = alpha; d_be[b*50 + step] = beta; }
            float binv = 1.0f / fmaxf(beta, 1e-12f);
            for (int j = tid; j < MN; j += 1024) {
                float2 q = va[j];
                vb[j] = q;
                float2 v = fb[j];
                va[j] = make_float2(v.x*binv, v.y*binv);
            }
            __syncthreads();
            beta_prev = beta;
        }
    } else {
        // ---------- CG: va = r, vb = p, x in registers (2 elems/thread)
        float2 x0r = make_float2(0.f, 0.f), x1r = make_float2(0.f, 0.f);
        float part = 0.f;
        for (int j = tid; j < MN; j += 1024) {
            float w = lws[j];
            float2 rr = d_rhs[j];
            float2 bj = make_float2(w*rr.x, w*rr.y);
            va[j] = bj; vb[j] = bj;
            part += bj.x*bj.x + bj.y*bj.y;
        }
        __syncthreads();
        float rs = block_reduce(part, red);
        for (int it = 0; it < 50; ++it) {
            for (int i = tid; i < NFFT; i += 1024) {
                float2 val = make_float2(0.f, 0.f);
                if (i < MN) { float w = lws[i]; float2 p = vb[i]; val = make_float2(w*p.x, w*p.y); }
                fb[i] = val;
            }
            __syncthreads();
            fft_dif(fb, tid, 1024);
            for (int i = tid; i < NFFT; i += 1024) fb[i] = cmulf(fb[i], d_G[i]);
            __syncthreads();
            fft_dit_inv(fb, tid, 1024);
            part = 0.f;
            for (int j = tid; j < MN; j += 1024) {
                float w = lws[j] * (1.0f / 4096.0f);
                float2 p = vb[j];
                float2 ap = make_float2(w*fb[j].x + 0.1f*p.x, w*fb[j].y + 0.1f*p.y);
                part += p.x*ap.x + p.y*ap.y;
            }
            float pAp = block_reduce(part, red);
            float a = rs / pAp;
            part = 0.f;
            for (int j = tid; j < MN; j += 1024) {
                float w = lws[j] * (1.0f / 4096.0f);
                float2 p = vb[j];
                float2 ap = make_float2(w*fb[j].x + 0.1f*p.x, w*fb[j].y + 0.1f*p.y);
                if (j == tid) { x0r.x += a*p.x; x0r.y += a*p.y; }
                else          { x1r.x += a*p.x; x1r.y += a*p.y; }
                float2 r = va[j];
                r.x -= a*ap.x; r.y -= a*ap.y;
                va[j] = r;
                part += r.x*r.x + r.y*r.y;
            }
            float rsn = block_reduce(part, red);
            float sc = rsn / rs;
            for (int j = tid; j < MN; j += 1024) {
                float2 p = vb[j]; float2 r = va[j];
                vb[j] = make_float2(r.x + sc*p.x, r.y + sc*p.y);
            }
            __syncthreads();
            rs = rsn;
        }
        for (int j = tid; j < MN; j += 1024) {
            float2 xv = (j == tid) ? x0r : x1r;
            d_wb[j] = make_float2(lws[j]*xv.x, lws[j]*xv.y);
        }
    }
}

// ---------------- K5: 64 tridiag eigensolves (tqli, first-row eigvec tracking) -> logdet
__global__ __launch_bounds__(64) void k_eig(const float* __restrict__ d_al,
                                            const float* __restrict__ d_be,
                                            const float* __restrict__ d_nz2,
                                            float* __restrict__ d_ld) {
    __shared__ float sd[50*64], se[50*64], sz[50*64];
    int t = threadIdx.x;
    for (int i = 0; i < 50; ++i) {
        sd[i*64+t] = d_al[t*50+i];
        se[i*64+t] = (i < 49) ? d_be[t*50+i] : 0.0f;
        sz[i*64+t] = (i == 0) ? 1.0f : 0.0f;
    }
    const int n = 50;
    #define D_(i) sd[(i)*64+t]
    #define E_(i) se[(i)*64+t]
    #define Z_(i) sz[(i)*64+t]
    for (int l = 0; l < n; ++l) {
        int iter = 0, m;
        do {
            for (m = l; m < n-1; ++m) {
                float dv = fabsf(D_(m)) + fabsf(D_(m+1));
                if (fabsf(E_(m)) <= 1.1920929e-07f * dv) break;
            }
            if (m != l) {
                if (++iter > 80) break;
                float g = (D_(l+1) - D_(l)) / (2.0f * E_(l));
                float r = hypotf(g, 1.0f);
                g = D_(m) - D_(l) + E_(l) / (g + copysignf(r, g));
                float s = 1.0f, c = 1.0f, p = 0.0f;
                int i; float rr = 1.0f;
                for (i = m-1; i >= l; --i) {
                    float f = s * E_(i);
                    float bb = c * E_(i);
                    rr = hypotf(f, g);
                    E_(i+1) = rr;
                    if (rr == 0.0f) { D_(i+1) -= p; E_(m) = 0.0f; break; }
                    s = f / rr; c = g / rr;
                    g = D_(i+1) - p;
                    float r2 = (D_(i) - g) * s + 2.0f * c * bb;
                    p = s * r2;
                    D_(i+1) = g + p;
                    g = c * r2 - bb;
                    float zf = Z_(i+1);
                    Z_(i+1) = s * Z_(i) + c * zf;
                    Z_(i)   = c * Z_(i) - s * zf;
                }
                if (rr == 0.0f && i >= l) continue;
                D_(l) -= p; E_(l) = g; E_(m) = 0.0f;
            }
        } while (m != l);
    }
    float quad = 0.f;
    for (int j = 0; j < n; ++j) {
        float ev = fmaxf(D_(j), 1e-18f);
        float w = Z_(j);
        quad += w * w * logf(ev);
    }
    quad *= d_nz2[t];
    #pragma unroll
    for (int off = 32; off > 0; off >>= 1) quad += __shfl_down(quad, off, 64);
    if (t == 0) *d_ld = quad / 64.0f + (-37725.5542f); // + N*log(sigma^2)
    #undef D_
    #undef E_
    #undef Z_
}

// ---------------- K6: mean[b] = Re sum_k exp(i*2pi*h*xnew_b*(k-768)) * wb_k
__global__ void k_mean(const float* __restrict__ xn, const float2* __restrict__ d_wb,
                       float* __restrict__ out) {
    int row = blockIdx.x * 64 + (threadIdx.x >> 2);
    int sub = threadIdx.x & 3;
    float xv = xn[row];
    float acc = 0.f;
    for (int k = sub; k < MN; k += 4) {
        float ph = CW * (xv * (float)(k - 768));
        float s, c; __sincosf(ph, &s, &c);
        float2 w = d_wb[k];
        acc += c * w.x - s * w.y;
    }
    acc += __shfl_down(acc, 2, 4);
    acc += __shfl_down(acc, 1, 4);
    if (sub == 0) out[row] = acc;
}

// ---------------- K7: t1 = sum_n y_n*(y_n - Re(F wb)_n)*10
__global__ void k_t1(const float* __restrict__ x, const float* __restrict__ y,
                     const float2* __restrict__ d_wb, float* __restrict__ d_t1) {
    int n = blockIdx.x * 256 + threadIdx.x;
    float xv = x[n], yv = y[n];
    float acc = 0.f;
    for (int k = 0; k < MN; ++k) {
        float ph = CW * (xv * (float)(k - 768));
        float s, c; __sincosf(ph, &s, &c);
        float2 w = d_wb[k];
        acc += c * w.x - s * w.y;
    }
    float contrib = yv * (yv - acc) * 10.0f;
    #pragma unroll
    for (int off = 32; off > 0; off >>= 1) contrib += __shfl_down(contrib, off, 64);
    if ((threadIdx.x & 63) == 0) atomicAdd(d_t1, contrib);
}

// ---------------- K8: lml
__global__ void k_final(const float* __restrict__ d_t1, const float* __restrict__ d_ld,
                        float* __restrict__ out) {
    if (threadIdx.x == 0)
        out[4096] = -0.5f * (*d_t1) - 0.5f * (*d_ld) - 15055.8889f; // -0.5*N*log(2pi)
}

extern "C" void kernel_launch(void* const* d_in, const int* in_sizes, int n_in,
                              void* d_out, int out_size, void* d_ws, size_t ws_size,
                              hipStream_t stream) {
    const float* d_x  = (const float*)d_in[0];
    const float* d_y  = (const float*)d_in[1];
    const float* d_xn = (const float*)d_in[2];
    const float* d_z  = (const float*)d_in[3];
    float* out = (float*)d_out;
    char* w = (char*)d_ws;
    float2* d_v   = (float2*)(w + 0);       // 3073 c64
    float2* d_G   = (float2*)(w + 24832);   // 4096 c64
    float2* d_rhs = (float2*)(w + 57600);   // 1537 c64
    float2* d_wb  = (float2*)(w + 70144);   // 1537 c64
    float*  d_al  = (float*) (w + 82688);   // 64x50
    float*  d_be  = (float*) (w + 95488);   // 64x50
    float*  d_nz2 = (float*) (w + 108288);  // 64
    float*  d_t1  = (float*) (w + 108544);  // 1 (accum)
    float*  d_ld  = (float*) (w + 108800);  // 1

    hipMemsetAsync(d_v,   0, 3073 * sizeof(float2), stream);
    hipMemsetAsync(d_rhs, 0, MN   * sizeof(float2), stream);
    hipMemsetAsync(d_t1,  0, sizeof(float), stream);

    k_vfull <<<dim3(13, 16), 256, 0, stream>>>(d_x, d_v);
    k_fhy   <<<dim3(7, 16),  256, 0, stream>>>(d_x, d_y, d_rhs);
    k_buildG<<<1, 1024, 0, stream>>>(d_v, d_G);
    k_solve <<<65, 1024, 0, stream>>>(d_G, d_rhs, d_z, d_wb, d_al, d_be, d_nz2);
    k_eig   <<<1, 64, 0, stream>>>(d_al, d_be, d_nz2, d_ld);
    k_mean  <<<64, 256, 0, stream>>>(d_xn, d_wb, out);
    k_t1    <<<64, 256, 0, stream>>>(d_x, d_y, d_wb, d_t1);
    k_final <<<1, 64, 0, stream>>>(d_t1, d_ld, out);
}

// Round 2
// 992.924 us; speedup vs baseline: 2.2643x; 2.2643x over previous
//
#include <hip/hip_runtime.h>
#include <math.h>

#define MN 1537          // M_NODES
#define NFFT 4096
#define CW 0.06283185307179587f   // 2*pi*h
#define W4096 1.5339807878856412e-3f // 2*pi/4096

__device__ inline float2 cmulf(float2 a, float2 b) {
    return make_float2(a.x*b.x - a.y*b.y, a.x*b.y + a.y*b.x);
}

__device__ inline float ws_at(int k) {
    float xi = 0.01f * (float)(k - 768);
    float t  = 0.31415926535897931f * xi;      // pi*ell*xi, ell=0.1
    float S  = 0.25066282746310002f * expf(-2.0f * t * t); // sqrt(2pi)*ell
    return sqrtf(0.01f * S);
}

// ---------------- FFT: DIF forward (natural -> bitrev), DIT inverse (bitrev -> natural)
__device__ void fft_dif(float2* buf, int tid, int nthr) {
    for (int s = 11; s >= 0; --s) {
        int half = 1 << s;
        for (int t = tid; t < 2048; t += nthr) {
            int pos = t & (half - 1);
            int i0 = ((t >> s) << (s + 1)) + pos;
            int i1 = i0 + half;
            float2 a = buf[i0], b = buf[i1];
            float ang = -W4096 * (float)(pos << (11 - s));
            float sn, cs; __sincosf(ang, &sn, &cs);
            buf[i0] = make_float2(a.x + b.x, a.y + b.y);
            float2 d = make_float2(a.x - b.x, a.y - b.y);
            buf[i1] = cmulf(d, make_float2(cs, sn));
        }
        __syncthreads();
    }
}

__device__ void fft_dit_inv(float2* buf, int tid, int nthr) {
    for (int s = 0; s <= 11; ++s) {
        int half = 1 << s;
        for (int t = tid; t < 2048; t += nthr) {
            int pos = t & (half - 1);
            int i0 = ((t >> s) << (s + 1)) + pos;
            int i1 = i0 + half;
            float ang = W4096 * (float)(pos << (11 - s));
            float sn, cs; __sincosf(ang, &sn, &cs);
            float2 a = buf[i0];
            float2 b = cmulf(buf[i1], make_float2(cs, sn));
            buf[i0] = make_float2(a.x + b.x, a.y + b.y);
            buf[i1] = make_float2(a.x - b.x, a.y - b.y);
        }
        __syncthreads();
    }
}

// ---------------- block-wide sum reduce (1024 threads = 16 waves), result to all
__device__ float block_reduce(float v, volatile float* scratch) {
    int lane = threadIdx.x & 63;
    int wid  = threadIdx.x >> 6;
    #pragma unroll
    for (int off = 32; off > 0; off >>= 1) v += __shfl_down(v, off, 64);
    if (lane == 0) scratch[wid] = v;
    __syncthreads();
    if (wid == 0) {
        float s = (lane < (int)(blockDim.x >> 6)) ? scratch[lane] : 0.0f;
        #pragma unroll
        for (int off = 8; off > 0; off >>= 1) s += __shfl_down(s, off, 64);
        if (lane == 0) scratch[16] = s;
    }
    __syncthreads();
    return scratch[16];
}

// ---------------- K1: vfull[p] = sum_n exp(i*2pi*h*x_n*p), p = idx-1536
__global__ void k_vfull(const float* __restrict__ x, float2* __restrict__ d_v) {
    int pi = blockIdx.x * 256 + threadIdx.x;
    if (pi >= 3073) return;
    float p = (float)(pi - 1536);
    int n0 = blockIdx.y * 1024;
    float sx = 0.f, sy = 0.f;
    for (int n = n0; n < n0 + 1024; ++n) {
        float ph = CW * (x[n] * p);
        float s, c; __sincosf(ph, &s, &c);
        sx += c; sy += s;
    }
    atomicAdd(&d_v[pi].x, sx);
    atomicAdd(&d_v[pi].y, sy);
}

// ---------------- K2: rhsraw[k] = sum_n exp(-i*2pi*h*x_n*(k-768)) * y_n
__global__ void k_fhy(const float* __restrict__ x, const float* __restrict__ y,
                      float2* __restrict__ d_rhs) {
    int k = blockIdx.x * 256 + threadIdx.x;
    if (k >= MN) return;
    float kk = (float)(k - 768);
    int n0 = blockIdx.y * 1024;
    float sx = 0.f, sy = 0.f;
    for (int n = n0; n < n0 + 1024; ++n) {
        float ph = CW * (x[n] * kk);
        float s, c; __sincosf(ph, &s, &c);
        sx += c * y[n]; sy -= s * y[n];
    }
    atomicAdd(&d_rhs[k].x, sx);
    atomicAdd(&d_rhs[k].y, sy);
}

// ---------------- K3: G = FFT4096(g), bit-reversed order, g[t mod 4096] = v_{-t}
__global__ __launch_bounds__(1024) void k_buildG(const float2* __restrict__ d_v,
                                                 float2* __restrict__ d_G) {
    __shared__ float2 buf[NFFT];
    int tid = threadIdx.x;
    for (int i = tid; i < NFFT; i += 1024) {
        float2 val = make_float2(0.f, 0.f);
        if (i == 0)            val = d_v[1536];
        else if (i <= 1536)    val = d_v[1536 - i];
        else if (i >= 2560)    val = d_v[5632 - i];   // v_{4096-i}
        buf[i] = val;
    }
    __syncthreads();
    fft_dif(buf, tid, 1024);
    for (int i = tid; i < NFFT; i += 1024) d_G[i] = buf[i];
}

// ---------------- K4: blocks 0..63 = Lanczos per probe; block 64 = CG
__global__ __launch_bounds__(1024) void k_solve(
    const float2* __restrict__ d_G, const float2* __restrict__ d_rhs,
    const float* __restrict__ d_z, float2* __restrict__ d_wb,
    float* __restrict__ d_al, float* __restrict__ d_be, float* __restrict__ d_nz2)
{
    __shared__ float2 fb[NFFT];
    __shared__ float2 va[MN];
    __shared__ float2 vb[MN];
    __shared__ float  lws[MN];
    __shared__ float  red[17];
    int tid = threadIdx.x;
    int b = blockIdx.x;
    for (int i = tid; i < MN; i += 1024) lws[i] = ws_at(i);
    __syncthreads();

    if (b < 64) {
        // ---------- Lanczos: va = q, vb = q_prev, v lives in fb[0:MN]
        float part = 0.f;
        for (int j = tid; j < MN; j += 1024) {
            float zv = d_z[b * MN + j];
            float s = (zv > 0.f) ? 1.f : ((zv < 0.f) ? -1.f : 0.f);
            va[j] = make_float2(s, 0.f);
            part += s * s;
        }
        __syncthreads();
        float nz2 = block_reduce(part, red);
        if (tid == 0) d_nz2[b] = nz2;
        float qs = 1.0f / sqrtf(nz2);
        for (int j = tid; j < MN; j += 1024) {
            float2 q = va[j];
            va[j] = make_float2(q.x * qs, q.y * qs);
            vb[j] = make_float2(0.f, 0.f);
        }
        __syncthreads();
        float beta_prev = 0.f;
        for (int step = 0; step < 50; ++step) {
            for (int i = tid; i < NFFT; i += 1024) {
                float2 val = make_float2(0.f, 0.f);
                if (i < MN) { float w = lws[i]; float2 q = va[i]; val = make_float2(w*q.x, w*q.y); }
                fb[i] = val;
            }
            __syncthreads();
            fft_dif(fb, tid, 1024);
            for (int i = tid; i < NFFT; i += 1024) fb[i] = cmulf(fb[i], d_G[i]);
            __syncthreads();
            fft_dit_inv(fb, tid, 1024);
            part = 0.f;
            for (int j = tid; j < MN; j += 1024) {
                float cf = lws[j] * (10.0f / 4096.0f); // (1/sigma^2) * (1/N)
                float2 q = va[j], qp = vb[j];
                float2 v = make_float2(q.x + cf*fb[j].x - beta_prev*qp.x,
                                       q.y + cf*fb[j].y - beta_prev*qp.y);
                fb[j] = v;
                part += q.x*v.x + q.y*v.y;
            }
            float alpha = block_reduce(part, red);
            part = 0.f;
            for (int j = tid; j < MN; j += 1024) {
                float2 q = va[j];
                float2 v = fb[j];
                v.x -= alpha*q.x; v.y -= alpha*q.y;
                fb[j] = v;
                part += v.x*v.x + v.y*v.y;
            }
            float nv = block_reduce(part, red);
            float beta = sqrtf(nv);
            if (tid == 0) { d_al[b*50 + step] = alpha; d_be[b*50 + step] = beta; }
            float binv = 1.0f / fmaxf(beta, 1e-12f);
            for (int j = tid; j < MN; j += 1024) {
                float2 q = va[j];
                vb[j] = q;
                float2 v = fb[j];
                va[j] = make_float2(v.x*binv, v.y*binv);
            }
            __syncthreads();
            beta_prev = beta;
        }
    } else {
        // ---------- CG: va = r, vb = p, x in registers (2 elems/thread)
        float2 x0r = make_float2(0.f, 0.f), x1r = make_float2(0.f, 0.f);
        float part = 0.f;
        for (int j = tid; j < MN; j += 1024) {
            float w = lws[j];
            float2 rr = d_rhs[j];
            float2 bj = make_float2(w*rr.x, w*rr.y);
            va[j] = bj; vb[j] = bj;
            part += bj.x*bj.x + bj.y*bj.y;
        }
        __syncthreads();
        float rs = block_reduce(part, red);
        for (int it = 0; it < 50; ++it) {
            for (int i = tid; i < NFFT; i += 1024) {
                float2 val = make_float2(0.f, 0.f);
                if (i < MN) { float w = lws[i]; float2 p = vb[i]; val = make_float2(w*p.x, w*p.y); }
                fb[i] = val;
            }
            __syncthreads();
            fft_dif(fb, tid, 1024);
            for (int i = tid; i < NFFT; i += 1024) fb[i] = cmulf(fb[i], d_G[i]);
            __syncthreads();
            fft_dit_inv(fb, tid, 1024);
            part = 0.f;
            for (int j = tid; j < MN; j += 1024) {
                float w = lws[j] * (1.0f / 4096.0f);
                float2 p = vb[j];
                float2 ap = make_float2(w*fb[j].x + 0.1f*p.x, w*fb[j].y + 0.1f*p.y);
                part += p.x*ap.x + p.y*ap.y;
            }
            float pAp = block_reduce(part, red);
            float a = rs / pAp;
            part = 0.f;
            for (int j = tid; j < MN; j += 1024) {
                float w = lws[j] * (1.0f / 4096.0f);
                float2 p = vb[j];
                float2 ap = make_float2(w*fb[j].x + 0.1f*p.x, w*fb[j].y + 0.1f*p.y);
                if (j == tid) { x0r.x += a*p.x; x0r.y += a*p.y; }
                else          { x1r.x += a*p.x; x1r.y += a*p.y; }
                float2 r = va[j];
                r.x -= a*ap.x; r.y -= a*ap.y;
                va[j] = r;
                part += r.x*r.x + r.y*r.y;
            }
            float rsn = block_reduce(part, red);
            float sc = rsn / rs;
            for (int j = tid; j < MN; j += 1024) {
                float2 p = vb[j]; float2 r = va[j];
                vb[j] = make_float2(r.x + sc*p.x, r.y + sc*p.y);
            }
            __syncthreads();
            rs = rsn;
        }
        for (int j = tid; j < MN; j += 1024) {
            float2 xv = (j == tid) ? x0r : x1r;
            d_wb[j] = make_float2(lws[j]*xv.x, lws[j]*xv.y);
        }
    }
}

// ---------------- K5: SLQ quadrature via Sturm bisection + Christoffel weights.
// One block per probe; lane j (j<50) finds j-th smallest eigenvalue of the
// 50x50 tridiagonal, weight = 1/sum_k p_k(lam)^2 (orthonormal poly recurrence).
__global__ __launch_bounds__(64) void k_slq(const float* __restrict__ d_al,
                                            const float* __restrict__ d_be,
                                            const float* __restrict__ d_nz2,
                                            float* __restrict__ d_quad) {
    __shared__ float a[50], e[50], e2[50];
    int b = blockIdx.x, t = threadIdx.x;
    if (t < 50) {
        a[t] = d_al[b*50 + t];
        float bv = (t < 49) ? d_be[b*50 + t] : 0.0f;
        e[t] = bv; e2[t] = bv * bv;
    }
    __syncthreads();
    float quad = 0.0f;
    if (t < 50) {
        // Gershgorin bounds
        float lo = 3.4e38f, hi = -3.4e38f;
        for (int i = 0; i < 50; ++i) {
            float r = ((i > 0) ? fabsf(e[i-1]) : 0.0f) + ((i < 49) ? fabsf(e[i]) : 0.0f);
            lo = fminf(lo, a[i] - r);
            hi = fmaxf(hi, a[i] + r);
        }
        // bisection for the t-th smallest eigenvalue (uniform trip count: no divergence)
        for (int it = 0; it < 46; ++it) {
            float mid = 0.5f * (lo + hi);
            int cnt = 0;
            float q = a[0] - mid;
            if (q < 0.0f) cnt++;
            #pragma unroll 10
            for (int k = 1; k < 50; ++k) {
                float dnm = q;
                if (fabsf(dnm) < 1e-30f) dnm = (dnm < 0.0f) ? -1e-30f : 1e-30f;
                q = (a[k] - mid) - e2[k-1] / dnm;
                if (q < 0.0f) cnt++;
            }
            if (cnt > t) hi = mid; else lo = mid;
        }
        float lam = 0.5f * (lo + hi);
        // Christoffel weight: w = 1 / sum_{k=0}^{49} p_k(lam)^2
        float pm = 0.0f, pc = 1.0f, s = 1.0f, bprev = 0.0f;
        for (int k = 0; k < 49; ++k) {
            float bk = fmaxf(e[k], 1e-30f);
            float pn = ((lam - a[k]) * pc - bprev * pm) / bk;
            pn = fminf(fmaxf(pn, -1e18f), 1e18f);   // clamp: avoids inf-inf NaN; huge s -> w~0
            s += pn * pn;
            pm = pc; pc = pn; bprev = bk;
        }
        float w = 1.0f / s;
        quad = w * logf(fmaxf(lam, 1e-18f));
    }
    // wave reduce over all 64 lanes (lanes >= 50 contribute 0)
    #pragma unroll
    for (int off = 32; off > 0; off >>= 1) quad += __shfl_down(quad, off, 64);
    if (t == 0) d_quad[b] = quad * d_nz2[b];
}

// ---------------- K6: mean[b] = Re sum_k exp(i*2pi*h*xnew_b*(k-768)) * wb_k
__global__ void k_mean(const float* __restrict__ xn, const float2* __restrict__ d_wb,
                       float* __restrict__ out) {
    int row = blockIdx.x * 64 + (threadIdx.x >> 2);
    int sub = threadIdx.x & 3;
    float xv = xn[row];
    float acc = 0.f;
    for (int k = sub; k < MN; k += 4) {
        float ph = CW * (xv * (float)(k - 768));
        float s, c; __sincosf(ph, &s, &c);
        float2 w = d_wb[k];
        acc += c * w.x - s * w.y;
    }
    acc += __shfl_down(acc, 2, 4);
    acc += __shfl_down(acc, 1, 4);
    if (sub == 0) out[row] = acc;
}

// ---------------- K7: t1 = sum_n y_n*(y_n - Re(F wb)_n)*10
__global__ void k_t1(const float* __restrict__ x, const float* __restrict__ y,
                     const float2* __restrict__ d_wb, float* __restrict__ d_t1) {
    int n = blockIdx.x * 256 + threadIdx.x;
    float xv = x[n], yv = y[n];
    float acc = 0.f;
    for (int k = 0; k < MN; ++k) {
        float ph = CW * (xv * (float)(k - 768));
        float s, c; __sincosf(ph, &s, &c);
        float2 w = d_wb[k];
        acc += c * w.x - s * w.y;
    }
    float contrib = yv * (yv - acc) * 10.0f;
    #pragma unroll
    for (int off = 32; off > 0; off >>= 1) contrib += __shfl_down(contrib, off, 64);
    if ((threadIdx.x & 63) == 0) atomicAdd(d_t1, contrib);
}

// ---------------- K8: lml = -0.5*t1 - 0.5*(mean(quad) + N log sigma^2) - 0.5*N*log(2pi)
__global__ void k_final(const float* __restrict__ d_t1, const float* __restrict__ d_quad,
                        float* __restrict__ out) {
    int t = threadIdx.x;
    float q = d_quad[t];
    #pragma unroll
    for (int off = 32; off > 0; off >>= 1) q += __shfl_down(q, off, 64);
    if (t == 0) {
        float ld = q / 64.0f + (-37725.5542f);  // + N*log(sigma^2)
        out[4096] = -0.5f * (*d_t1) - 0.5f * ld - 15055.8889f; // - 0.5*N*log(2pi)
    }
}

extern "C" void kernel_launch(void* const* d_in, const int* in_sizes, int n_in,
                              void* d_out, int out_size, void* d_ws, size_t ws_size,
                              hipStream_t stream) {
    const float* d_x  = (const float*)d_in[0];
    const float* d_y  = (const float*)d_in[1];
    const float* d_xn = (const float*)d_in[2];
    const float* d_z  = (const float*)d_in[3];
    float* out = (float*)d_out;
    char* w = (char*)d_ws;
    float2* d_v   = (float2*)(w + 0);       // 3073 c64
    float2* d_G   = (float2*)(w + 24832);   // 4096 c64
    float2* d_rhs = (float2*)(w + 57600);   // 1537 c64
    float2* d_wb  = (float2*)(w + 70144);   // 1537 c64
    float*  d_al  = (float*) (w + 82688);   // 64x50
    float*  d_be  = (float*) (w + 95488);   // 64x50
    float*  d_nz2 = (float*) (w + 108288);  // 64
    float*  d_t1  = (float*) (w + 108544);  // 1 (accum)
    float*  d_quad= (float*) (w + 108800);  // 64

    hipMemsetAsync(d_v,   0, 3073 * sizeof(float2), stream);
    hipMemsetAsync(d_rhs, 0, MN   * sizeof(float2), stream);
    hipMemsetAsync(d_t1,  0, sizeof(float), stream);

    k_vfull <<<dim3(13, 16), 256, 0, stream>>>(d_x, d_v);
    k_fhy   <<<dim3(7, 16),  256, 0, stream>>>(d_x, d_y, d_rhs);
    k_buildG<<<1, 1024, 0, stream>>>(d_v, d_G);
    k_solve <<<65, 1024, 0, stream>>>(d_G, d_rhs, d_z, d_wb, d_al, d_be, d_nz2);
    k_slq   <<<64, 64, 0, stream>>>(d_al, d_be, d_nz2, d_quad);
    k_mean  <<<64, 256, 0, stream>>>(d_xn, d_wb, out);
    k_t1    <<<64, 256, 0, stream>>>(d_x, d_y, d_wb, d_t1);
    k_final <<<1, 64, 0, stream>>>(d_t1, d_quad, out);
}

// Round 3
// 955.866 us; speedup vs baseline: 2.3521x; 1.0388x over previous
//
#include <hip/hip_runtime.h>
#include <math.h>

#define MN 1537          // M_NODES
#define NFFT 4096
#define FBN (NFFT + NFFT/8)   // padded LDS size (float2 units)
#define CW 0.06283185307179587f      // 2*pi*h
#define W4096 1.5339807878856412e-3f // 2*pi/4096

__device__ __forceinline__ float2 cmulf(float2 a, float2 b) {
    return make_float2(a.x*b.x - a.y*b.y, a.x*b.y + a.y*b.x);
}
__device__ __forceinline__ float2 cadd(float2 a, float2 b){ return make_float2(a.x+b.x, a.y+b.y); }
__device__ __forceinline__ float2 csub(float2 a, float2 b){ return make_float2(a.x-b.x, a.y-b.y); }
__device__ __forceinline__ float2 mulnegi(float2 z){ return make_float2(z.y, -z.x); }  // z * (-i)
__device__ __forceinline__ float2 mulposi(float2 z){ return make_float2(-z.y, z.x); }  // z * (+i)
__device__ __forceinline__ int PHI(int i){ return i + (i >> 3); }  // bank-conflict pad

__device__ __forceinline__ float ws_at(int k) {
    float xi = 0.01f * (float)(k - 768);
    float t  = 0.31415926535897931f * xi;      // pi*ell*xi
    float S  = 0.25066282746310002f * expf(-2.0f * t * t); // sqrt(2pi)*ell
    return sqrtf(0.01f * S);
}

// ---------------- radix-8 fused stages (3 radix-2 stages in registers, in place)
// forward DIF triple covering radix-2 stages (S, S-1, S-2); S in {11,8,5,2}; tt in [0,512)
template<int S>
__device__ __forceinline__ void fwd8(float2* fb, int tt){
    const int Q = 1 << (S-2);
    const int p = tt & (Q-1);
    const int g = tt >> (S-2);
    const int base = (g << (S+1)) + p;
    float2 a0 = fb[PHI(base      )], a1 = fb[PHI(base +   Q)];
    float2 a2 = fb[PHI(base + 2*Q)], a3 = fb[PHI(base + 3*Q)];
    float2 a4 = fb[PHI(base + 4*Q)], a5 = fb[PHI(base + 5*Q)];
    float2 a6 = fb[PHI(base + 6*Q)], a7 = fb[PHI(base + 7*Q)];
    float ang = -W4096 * (float)(p << (11-S));
    float sn, cs; __sincosf(ang, &sn, &cs);
    float2 w1 = make_float2(cs, sn);
    float2 w2 = cmulf(w1, w1);
    float2 w4 = cmulf(w2, w2);
    const float R = 0.70710678118654752f;
    float2 w1c1 = cmulf(w1, make_float2( R, -R));   // w1 * e^{-i pi/4}
    float2 w1c3 = cmulf(w1, make_float2(-R, -R));   // w1 * e^{-i 3pi/4}
    // stage S (half 4Q): pairs (k, k+4), tw = w1 * c8^k
    float2 b0 = cadd(a0,a4), b1 = cadd(a1,a5), b2 = cadd(a2,a6), b3 = cadd(a3,a7);
    float2 b4 = cmulf(csub(a0,a4), w1);
    float2 b5 = cmulf(csub(a1,a5), w1c1);
    float2 b6 = mulnegi(cmulf(csub(a2,a6), w1));
    float2 b7 = cmulf(csub(a3,a7), w1c3);
    // stage S-1 (half 2Q): pairs (0,2),(1,3),(4,6),(5,7); tw = w2, w2*(-i)
    float2 c0 = cadd(b0,b2), c2 = cmulf(csub(b0,b2), w2);
    float2 c1 = cadd(b1,b3), c3 = mulnegi(cmulf(csub(b1,b3), w2));
    float2 c4 = cadd(b4,b6), c6 = cmulf(csub(b4,b6), w2);
    float2 c5 = cadd(b5,b7), c7 = mulnegi(cmulf(csub(b5,b7), w2));
    // stage S-2 (half Q): pairs (2j, 2j+1); tw = w4
    fb[PHI(base      )] = cadd(c0,c1);
    fb[PHI(base +   Q)] = cmulf(csub(c0,c1), w4);
    fb[PHI(base + 2*Q)] = cadd(c2,c3);
    fb[PHI(base + 3*Q)] = cmulf(csub(c2,c3), w4);
    fb[PHI(base + 4*Q)] = cadd(c4,c5);
    fb[PHI(base + 5*Q)] = cmulf(csub(c4,c5), w4);
    fb[PHI(base + 6*Q)] = cadd(c6,c7);
    fb[PHI(base + 7*Q)] = cmulf(csub(c6,c7), w4);
}

// inverse DIT triple covering radix-2 stages (S, S+1, S+2); S in {0,3,6,9}
template<int S>
__device__ __forceinline__ void inv8(float2* fb, int tt){
    const int Q = 1 << S;
    const int p = tt & (Q-1);
    const int g = tt >> S;
    const int base = (g << (S+3)) + p;
    float2 a0 = fb[PHI(base      )], a1 = fb[PHI(base +   Q)];
    float2 a2 = fb[PHI(base + 2*Q)], a3 = fb[PHI(base + 3*Q)];
    float2 a4 = fb[PHI(base + 4*Q)], a5 = fb[PHI(base + 5*Q)];
    float2 a6 = fb[PHI(base + 6*Q)], a7 = fb[PHI(base + 7*Q)];
    float ang = W4096 * (float)(p << (9-S));
    float sn, cs; __sincosf(ang, &sn, &cs);
    float2 u1 = make_float2(cs, sn);
    float2 u2 = cmulf(u1, u1);
    float2 u4 = cmulf(u2, u2);
    const float R = 0.70710678118654752f;
    float2 u1c1 = cmulf(u1, make_float2( R,  R));   // u1 * e^{+i pi/4}
    float2 u1c3 = cmulf(u1, make_float2(-R,  R));   // u1 * e^{+i 3pi/4}
    float2 m;
    // stage S (half Q): pairs (2j, 2j+1); tw u4 on odd
    m = cmulf(a1, u4); float2 t0 = cadd(a0,m), t1 = csub(a0,m);
    m = cmulf(a3, u4); float2 t2 = cadd(a2,m), t3 = csub(a2,m);
    m = cmulf(a5, u4); float2 t4 = cadd(a4,m), t5 = csub(a4,m);
    m = cmulf(a7, u4); float2 t6 = cadd(a6,m), t7 = csub(a6,m);
    // stage S+1 (half 2Q): pairs (0,2) tw u2; (1,3) tw u2*(+i); same for 4..7
    m = cmulf(t2, u2);          float2 e0 = cadd(t0,m), e2 = csub(t0,m);
    m = mulposi(cmulf(t3, u2)); float2 e1 = cadd(t1,m), e3 = csub(t1,m);
    m = cmulf(t6, u2);          float2 e4 = cadd(t4,m), e6 = csub(t4,m);
    m = mulposi(cmulf(t7, u2)); float2 e5 = cadd(t5,m), e7 = csub(t5,m);
    // stage S+2 (half 4Q): pairs (k, k+4); tw u1 * c8conj^k
    m = cmulf(e4, u1);          fb[PHI(base      )] = cadd(e0,m); fb[PHI(base + 4*Q)] = csub(e0,m);
    m = cmulf(e5, u1c1);        fb[PHI(base +   Q)] = cadd(e1,m); fb[PHI(base + 5*Q)] = csub(e1,m);
    m = mulposi(cmulf(e6, u1)); fb[PHI(base + 2*Q)] = cadd(e2,m); fb[PHI(base + 6*Q)] = csub(e2,m);
    m = cmulf(e7, u1c3);        fb[PHI(base + 3*Q)] = cadd(e3,m); fb[PHI(base + 7*Q)] = csub(e3,m);
}

// full circular convolution: fb (filled, padded layout) -> ifft(fft(fb) .* G), scaled by 4096
__device__ __forceinline__ void conv_fft(float2* fb, const float2* __restrict__ G, int tid){
    __syncthreads();                       // fill visible
    if (tid < 512) fwd8<11>(fb, tid); __syncthreads();
    if (tid < 512) fwd8<8 >(fb, tid); __syncthreads();
    if (tid < 512) fwd8<5 >(fb, tid); __syncthreads();
    if (tid < 512) fwd8<2 >(fb, tid); __syncthreads();
    #pragma unroll
    for (int k = 0; k < 4; ++k){ int i = tid + k*1024; fb[PHI(i)] = cmulf(fb[PHI(i)], G[i]); }
    __syncthreads();
    if (tid < 512) inv8<0>(fb, tid); __syncthreads();
    if (tid < 512) inv8<3>(fb, tid); __syncthreads();
    if (tid < 512) inv8<6>(fb, tid); __syncthreads();
    if (tid < 512) inv8<9>(fb, tid); __syncthreads();
}

// ---------------- block-wide sum reduce (1024 threads = 16 waves), result to all
__device__ float block_reduce(float v, volatile float* scratch) {
    int lane = threadIdx.x & 63;
    int wid  = threadIdx.x >> 6;
    #pragma unroll
    for (int off = 32; off > 0; off >>= 1) v += __shfl_down(v, off, 64);
    if (lane == 0) scratch[wid] = v;
    __syncthreads();
    if (wid == 0) {
        float s = (lane < 16) ? scratch[lane] : 0.0f;
        #pragma unroll
        for (int off = 8; off > 0; off >>= 1) s += __shfl_down(s, off, 64);
        if (lane == 0) scratch[16] = s;
    }
    __syncthreads();
    return scratch[16];
}

// ---------------- K1: one wave per output column; no atomics, no memset
// waves [0,3073): d_v[p] = sum_n exp(+i*CW*x_n*(p-1536))
// waves [3073, 3073+MN): d_rhs[k] = sum_n exp(-i*CW*x_n*(k-768)) * y_n
__global__ __launch_bounds__(256) void k_prep(const float* __restrict__ x, const float* __restrict__ y,
                                              float2* __restrict__ d_v, float2* __restrict__ d_rhs){
    int gw = (blockIdx.x * 256 + threadIdx.x) >> 6;
    int lane = threadIdx.x & 63;
    if (gw >= 3073 + MN) return;
    bool is_v = gw < 3073;
    float pk = is_v ? (float)(gw - 1536) : (float)(gw - 3073 - 768);
    float sx = 0.f, sy = 0.f;
    if (is_v){
        for (int j = 0; j < 256; ++j){
            int n = j*64 + lane;
            float ph = CW * (x[n] * pk);
            float s, c; __sincosf(ph, &s, &c);
            sx += c; sy += s;
        }
    } else {
        for (int j = 0; j < 256; ++j){
            int n = j*64 + lane;
            float yv = y[n];
            float ph = CW * (x[n] * pk);
            float s, c; __sincosf(ph, &s, &c);
            sx += c*yv; sy -= s*yv;
        }
    }
    #pragma unroll
    for (int off = 32; off > 0; off >>= 1){
        sx += __shfl_down(sx, off, 64);
        sy += __shfl_down(sy, off, 64);
    }
    if (lane == 0){
        if (is_v) d_v[gw] = make_float2(sx, sy);
        else      d_rhs[gw - 3073] = make_float2(sx, sy);
    }
}

// ---------------- K2: G = FFT4096(g) in fused-radix-8 scrambled order
__global__ __launch_bounds__(1024) void k_buildG(const float2* __restrict__ d_v,
                                                 float2* __restrict__ d_G) {
    __shared__ float2 fb[FBN];
    int tid = threadIdx.x;
    #pragma unroll
    for (int k = 0; k < 4; ++k){
        int i = tid + k*1024;
        float2 val = make_float2(0.f, 0.f);
        if (i == 0)            val = d_v[1536];
        else if (i <= 1536)    val = d_v[1536 - i];
        else if (i >= 2560)    val = d_v[5632 - i];   // v_{i-4096}
        fb[PHI(i)] = val;
    }
    __syncthreads();
    if (tid < 512) fwd8<11>(fb, tid); __syncthreads();
    if (tid < 512) fwd8<8 >(fb, tid); __syncthreads();
    if (tid < 512) fwd8<5 >(fb, tid); __syncthreads();
    if (tid < 512) fwd8<2 >(fb, tid); __syncthreads();
    #pragma unroll
    for (int k = 0; k < 4; ++k){ int i = tid + k*1024; d_G[i] = fb[PHI(i)]; }
}

// ---------------- K3: blocks 0..63 = Lanczos per probe; block 64 = CG.
// Vectors live in registers: thread t owns j = t and j = t+1024 (if < MN).
__global__ __launch_bounds__(1024) void k_solve(
    const float2* __restrict__ d_G, const float2* __restrict__ d_rhs,
    const float* __restrict__ d_z, float2* __restrict__ d_wb,
    float* __restrict__ d_al, float* __restrict__ d_be, float* __restrict__ d_nz2)
{
    __shared__ float2 fb[FBN];
    __shared__ float  red[17];
    int tid = threadIdx.x;
    int b = blockIdx.x;
    bool has1 = (tid + 1024) < MN;
    float w0  = ws_at(tid);
    float w1v = has1 ? ws_at(tid + 1024) : 0.f;

    if (b < 64) {
        // ---------- Lanczos
        float2 q0, q1, qp0, qp1;
        float part = 0.f;
        {
            float zv = d_z[b*MN + tid];
            float s = (zv > 0.f) ? 1.f : ((zv < 0.f) ? -1.f : 0.f);
            q0 = make_float2(s, 0.f); part += s*s;
        }
        if (has1){
            float zv = d_z[b*MN + tid + 1024];
            float s = (zv > 0.f) ? 1.f : ((zv < 0.f) ? -1.f : 0.f);
            q1 = make_float2(s, 0.f); part += s*s;
        } else q1 = make_float2(0.f, 0.f);
        float nz2 = block_reduce(part, red);
        if (tid == 0) d_nz2[b] = nz2;
        float qs = 1.0f / sqrtf(nz2);
        q0.x *= qs; q0.y *= qs; q1.x *= qs; q1.y *= qs;
        qp0 = make_float2(0.f, 0.f); qp1 = make_float2(0.f, 0.f);
        float bp = 0.f;
        const float cf0 = w0  * (10.0f / 4096.0f);
        const float cf1 = w1v * (10.0f / 4096.0f);
        for (int step = 0; step < 50; ++step) {
            fb[PHI(tid)]        = make_float2(w0*q0.x, w0*q0.y);
            fb[PHI(tid + 1024)] = make_float2(w1v*q1.x, w1v*q1.y);
            fb[PHI(tid + 2048)] = make_float2(0.f, 0.f);
            fb[PHI(tid + 3072)] = make_float2(0.f, 0.f);
            conv_fft(fb, d_G, tid);
            float2 c0v = fb[PHI(tid)];
            float2 c1v = has1 ? fb[PHI(tid + 1024)] : make_float2(0.f, 0.f);
            float2 v0 = make_float2(q0.x + cf0*c0v.x - bp*qp0.x,
                                    q0.y + cf0*c0v.y - bp*qp0.y);
            float2 v1 = make_float2(q1.x + cf1*c1v.x - bp*qp1.x,
                                    q1.y + cf1*c1v.y - bp*qp1.y);
            part = q0.x*v0.x + q0.y*v0.y + q1.x*v1.x + q1.y*v1.y;
            float alpha = block_reduce(part, red);
            v0.x -= alpha*q0.x; v0.y -= alpha*q0.y;
            v1.x -= alpha*q1.x; v1.y -= alpha*q1.y;
            part = v0.x*v0.x + v0.y*v0.y + v1.x*v1.x + v1.y*v1.y;
            float nv = block_reduce(part, red);
            float beta = sqrtf(nv);
            if (tid == 0) { d_al[b*50 + step] = alpha; d_be[b*50 + step] = beta; }
            float binv = 1.0f / fmaxf(beta, 1e-12f);
            qp0 = q0; qp1 = q1;
            q0 = make_float2(v0.x*binv, v0.y*binv);
            q1 = make_float2(v1.x*binv, v1.y*binv);
            bp = beta;
        }
    } else {
        // ---------- CG
        float2 r0, r1, p0, p1, x0, x1;
        float part = 0.f;
        {
            float2 rr = d_rhs[tid];
            r0 = make_float2(w0*rr.x, w0*rr.y);
            part += r0.x*r0.x + r0.y*r0.y;
        }
        if (has1){
            float2 rr = d_rhs[tid + 1024];
            r1 = make_float2(w1v*rr.x, w1v*rr.y);
            part += r1.x*r1.x + r1.y*r1.y;
        } else r1 = make_float2(0.f, 0.f);
        p0 = r0; p1 = r1;
        x0 = make_float2(0.f, 0.f); x1 = make_float2(0.f, 0.f);
        float rs = block_reduce(part, red);
        const float cf0 = w0  * (1.0f / 4096.0f);
        const float cf1 = w1v * (1.0f / 4096.0f);
        for (int it = 0; it < 50; ++it) {
            fb[PHI(tid)]        = make_float2(w0*p0.x, w0*p0.y);
            fb[PHI(tid + 1024)] = make_float2(w1v*p1.x, w1v*p1.y);
            fb[PHI(tid + 2048)] = make_float2(0.f, 0.f);
            fb[PHI(tid + 3072)] = make_float2(0.f, 0.f);
            conv_fft(fb, d_G, tid);
            float2 c0v = fb[PHI(tid)];
            float2 c1v = has1 ? fb[PHI(tid + 1024)] : make_float2(0.f, 0.f);
            float2 ap0 = make_float2(cf0*c0v.x + 0.1f*p0.x, cf0*c0v.y + 0.1f*p0.y);
            float2 ap1 = make_float2(cf1*c1v.x + 0.1f*p1.x, cf1*c1v.y + 0.1f*p1.y);
            part = p0.x*ap0.x + p0.y*ap0.y + p1.x*ap1.x + p1.y*ap1.y;
            float pAp = block_reduce(part, red);
            float a = rs / pAp;
            x0.x += a*p0.x; x0.y += a*p0.y; x1.x += a*p1.x; x1.y += a*p1.y;
            r0.x -= a*ap0.x; r0.y -= a*ap0.y; r1.x -= a*ap1.x; r1.y -= a*ap1.y;
            part = r0.x*r0.x + r0.y*r0.y + r1.x*r1.x + r1.y*r1.y;
            float rsn = block_reduce(part, red);
            float sc = rsn / rs;
            p0 = make_float2(r0.x + sc*p0.x, r0.y + sc*p0.y);
            p1 = make_float2(r1.x + sc*p1.x, r1.y + sc*p1.y);
            rs = rsn;
        }
        d_wb[tid] = make_float2(w0*x0.x, w0*x0.y);
        if (has1) d_wb[tid + 1024] = make_float2(w1v*x1.x, w1v*x1.y);
    }
}

// ---------------- K4: SLQ quadrature via Sturm bisection + Christoffel weights
__global__ __launch_bounds__(64) void k_slq(const float* __restrict__ d_al,
                                            const float* __restrict__ d_be,
                                            const float* __restrict__ d_nz2,
                                            float* __restrict__ d_quad) {
    __shared__ float a[50], e[50], e2[50];
    int b = blockIdx.x, t = threadIdx.x;
    if (t < 50) {
        a[t] = d_al[b*50 + t];
        float bv = (t < 49) ? d_be[b*50 + t] : 0.0f;
        e[t] = bv; e2[t] = bv * bv;
    }
    __syncthreads();
    float quad = 0.0f;
    if (t < 50) {
        float lo = 3.4e38f, hi = -3.4e38f;
        for (int i = 0; i < 50; ++i) {
            float r = ((i > 0) ? fabsf(e[i-1]) : 0.0f) + ((i < 49) ? fabsf(e[i]) : 0.0f);
            lo = fminf(lo, a[i] - r);
            hi = fmaxf(hi, a[i] + r);
        }
        for (int it = 0; it < 46; ++it) {
            float mid = 0.5f * (lo + hi);
            int cnt = 0;
            float q = a[0] - mid;
            if (q < 0.0f) cnt++;
            #pragma unroll 10
            for (int k = 1; k < 50; ++k) {
                float dnm = q;
                if (fabsf(dnm) < 1e-30f) dnm = (dnm < 0.0f) ? -1e-30f : 1e-30f;
                q = (a[k] - mid) - e2[k-1] / dnm;
                if (q < 0.0f) cnt++;
            }
            if (cnt > t) hi = mid; else lo = mid;
        }
        float lam = 0.5f * (lo + hi);
        float pm = 0.0f, pc = 1.0f, s = 1.0f, bprev = 0.0f;
        for (int k = 0; k < 49; ++k) {
            float bk = fmaxf(e[k], 1e-30f);
            float pn = ((lam - a[k]) * pc - bprev * pm) / bk;
            pn = fminf(fmaxf(pn, -1e18f), 1e18f);
            s += pn * pn;
            pm = pc; pc = pn; bprev = bk;
        }
        float w = 1.0f / s;
        quad = w * logf(fmaxf(lam, 1e-18f));
    }
    #pragma unroll
    for (int off = 32; off > 0; off >>= 1) quad += __shfl_down(quad, off, 64);
    if (t == 0) d_quad[b] = quad * d_nz2[b];
}

// ---------------- K5: fused mean (blocks 0..63) + t1 partials (blocks 64..127)
__global__ __launch_bounds__(256) void k_post(const float* __restrict__ x, const float* __restrict__ y,
                                              const float* __restrict__ xn, const float2* __restrict__ d_wb,
                                              float* __restrict__ out, float* __restrict__ d_t1p) {
    __shared__ float red4[4];
    int b = blockIdx.x, tid = threadIdx.x;
    if (b < 64) {
        int row = b*64 + (tid >> 2);
        int sub = tid & 3;
        float xv = xn[row];
        float acc = 0.f;
        for (int k = sub; k < MN; k += 4) {
            float ph = CW * (xv * (float)(k - 768));
            float s, c; __sincosf(ph, &s, &c);
            float2 w = d_wb[k];
            acc += c * w.x - s * w.y;
        }
        acc += __shfl_down(acc, 2, 4);
        acc += __shfl_down(acc, 1, 4);
        if (sub == 0) out[row] = acc;
    } else {
        int n = (b - 64)*256 + tid;
        float xv = x[n], yv = y[n];
        float acc = 0.f;
        for (int k = 0; k < MN; ++k) {
            float ph = CW * (xv * (float)(k - 768));
            float s, c; __sincosf(ph, &s, &c);
            float2 w = d_wb[k];
            acc += c * w.x - s * w.y;
        }
        float contrib = yv * (yv - acc) * 10.0f;
        #pragma unroll
        for (int off = 32; off > 0; off >>= 1) contrib += __shfl_down(contrib, off, 64);
        if ((tid & 63) == 0) red4[tid >> 6] = contrib;
        __syncthreads();
        if (tid == 0) d_t1p[b - 64] = red4[0] + red4[1] + red4[2] + red4[3];
    }
}

// ---------------- K6: lml
__global__ __launch_bounds__(64) void k_final(const float* __restrict__ d_t1p,
                                              const float* __restrict__ d_quad,
                                              float* __restrict__ out) {
    int t = threadIdx.x;
    float t1 = d_t1p[t];
    float q  = d_quad[t];
    #pragma unroll
    for (int off = 32; off > 0; off >>= 1) {
        t1 += __shfl_down(t1, off, 64);
        q  += __shfl_down(q,  off, 64);
    }
    if (t == 0) {
        float ld = q / 64.0f - 37725.5542f;           // + N*log(sigma^2)
        out[4096] = -0.5f * t1 - 0.5f * ld - 15055.8889f; // - 0.5*N*log(2pi)
    }
}

extern "C" void kernel_launch(void* const* d_in, const int* in_sizes, int n_in,
                              void* d_out, int out_size, void* d_ws, size_t ws_size,
                              hipStream_t stream) {
    const float* d_x  = (const float*)d_in[0];
    const float* d_y  = (const float*)d_in[1];
    const float* d_xn = (const float*)d_in[2];
    const float* d_z  = (const float*)d_in[3];
    float* out = (float*)d_out;
    char* w = (char*)d_ws;
    float2* d_v   = (float2*)(w + 0);       // 3073 c64
    float2* d_rhs = (float2*)(w + 24832);   // 1537 c64
    float2* d_G   = (float2*)(w + 37376);   // 4096 c64
    float2* d_wb  = (float2*)(w + 70144);   // 1537 c64
    float*  d_al  = (float*) (w + 82688);   // 64x50
    float*  d_be  = (float*) (w + 95488);   // 64x50
    float*  d_nz2 = (float*) (w + 108288);  // 64
    float*  d_quad= (float*) (w + 108544);  // 64
    float*  d_t1p = (float*) (w + 108800);  // 64

    k_prep  <<<1153, 256, 0, stream>>>(d_x, d_y, d_v, d_rhs);
    k_buildG<<<1, 1024, 0, stream>>>(d_v, d_G);
    k_solve <<<65, 1024, 0, stream>>>(d_G, d_rhs, d_z, d_wb, d_al, d_be, d_nz2);
    k_slq   <<<64, 64, 0, stream>>>(d_al, d_be, d_nz2, d_quad);
    k_post  <<<128, 256, 0, stream>>>(d_x, d_y, d_xn, d_wb, out, d_t1p);
    k_final <<<1, 64, 0, stream>>>(d_t1p, d_quad, out);
}

// Round 4
// 623.777 us; speedup vs baseline: 3.6043x; 1.5324x over previous
//
#include <hip/hip_runtime.h>
#include <math.h>

#define MN 1537          // M_NODES
#define NFFT 4096
#define FBN (NFFT + NFFT/8)   // padded LDS size (float2 units)
#define CW 0.06283185307179587f      // 2*pi*h
#define W4096 1.5339807878856412e-3f // 2*pi/4096

__device__ __forceinline__ float2 cmulf(float2 a, float2 b) {
    return make_float2(a.x*b.x - a.y*b.y, a.x*b.y + a.y*b.x);
}
__device__ __forceinline__ float2 cadd(float2 a, float2 b){ return make_float2(a.x+b.x, a.y+b.y); }
__device__ __forceinline__ float2 csub(float2 a, float2 b){ return make_float2(a.x-b.x, a.y-b.y); }
__device__ __forceinline__ float2 mulnegi(float2 z){ return make_float2(z.y, -z.x); }  // z * (-i)
__device__ __forceinline__ float2 mulposi(float2 z){ return make_float2(-z.y, z.x); }  // z * (+i)
__device__ __forceinline__ int PHI(int i){ return i + (i >> 3); }  // bank-conflict pad

__device__ __forceinline__ float ws_at(int k) {
    float xi = 0.01f * (float)(k - 768);
    float t  = 0.31415926535897931f * xi;      // pi*ell*xi
    float S  = 0.25066282746310002f * expf(-2.0f * t * t); // sqrt(2pi)*ell
    return sqrtf(0.01f * S);
}

// ---------------- radix-8 fused stages (3 radix-2 stages in registers, in place)
// forward DIF triple covering radix-2 stages (S, S-1, S-2); S in {11,8,5,2}; tt in [0,512)
// w1 = e^{-i*W4096*(p<<(11-S))}, p = tt & (2^(S-2)-1)   (precomputable per thread)
template<int S>
__device__ __forceinline__ void fwd8(float2* fb, int tt, float2 w1){
    const int Q = 1 << (S-2);
    const int p = tt & (Q-1);
    const int g = tt >> (S-2);
    const int base = (g << (S+1)) + p;
    float2 a0 = fb[PHI(base      )], a1 = fb[PHI(base +   Q)];
    float2 a2 = fb[PHI(base + 2*Q)], a3 = fb[PHI(base + 3*Q)];
    float2 a4 = fb[PHI(base + 4*Q)], a5 = fb[PHI(base + 5*Q)];
    float2 a6 = fb[PHI(base + 6*Q)], a7 = fb[PHI(base + 7*Q)];
    const float R = 0.70710678118654752f;
    float2 w2, w4, w1c1, w1c3;
    if (S == 2) {
        w1 = make_float2(1.f, 0.f); w2 = w1; w4 = w1;
        w1c1 = make_float2( R, -R); w1c3 = make_float2(-R, -R);
    } else {
        w2 = cmulf(w1, w1); w4 = cmulf(w2, w2);
        w1c1 = cmulf(w1, make_float2( R, -R));
        w1c3 = cmulf(w1, make_float2(-R, -R));
    }
    // stage S (half 4Q): pairs (k, k+4), tw = w1 * c8^k
    float2 b0 = cadd(a0,a4), b1 = cadd(a1,a5), b2 = cadd(a2,a6), b3 = cadd(a3,a7);
    float2 b4 = cmulf(csub(a0,a4), w1);
    float2 b5 = cmulf(csub(a1,a5), w1c1);
    float2 b6 = mulnegi(cmulf(csub(a2,a6), w1));
    float2 b7 = cmulf(csub(a3,a7), w1c3);
    // stage S-1 (half 2Q)
    float2 c0 = cadd(b0,b2), c2 = cmulf(csub(b0,b2), w2);
    float2 c1 = cadd(b1,b3), c3 = mulnegi(cmulf(csub(b1,b3), w2));
    float2 c4 = cadd(b4,b6), c6 = cmulf(csub(b4,b6), w2);
    float2 c5 = cadd(b5,b7), c7 = mulnegi(cmulf(csub(b5,b7), w2));
    // stage S-2 (half Q)
    fb[PHI(base      )] = cadd(c0,c1);
    fb[PHI(base +   Q)] = cmulf(csub(c0,c1), w4);
    fb[PHI(base + 2*Q)] = cadd(c2,c3);
    fb[PHI(base + 3*Q)] = cmulf(csub(c2,c3), w4);
    fb[PHI(base + 4*Q)] = cadd(c4,c5);
    fb[PHI(base + 5*Q)] = cmulf(csub(c4,c5), w4);
    fb[PHI(base + 6*Q)] = cadd(c6,c7);
    fb[PHI(base + 7*Q)] = cmulf(csub(c6,c7), w4);
}

// inverse DIT triple covering radix-2 stages (S, S+1, S+2); S in {0,3,6,9}
// u1 = e^{+i*W4096*(p<<(9-S))}, p = tt & (2^S - 1) = conj of matching fwd twiddle
template<int S>
__device__ __forceinline__ void inv8(float2* fb, int tt, float2 u1){
    const int Q = 1 << S;
    const int p = tt & (Q-1);
    const int g = tt >> S;
    const int base = (g << (S+3)) + p;
    float2 a0 = fb[PHI(base      )], a1 = fb[PHI(base +   Q)];
    float2 a2 = fb[PHI(base + 2*Q)], a3 = fb[PHI(base + 3*Q)];
    float2 a4 = fb[PHI(base + 4*Q)], a5 = fb[PHI(base + 5*Q)];
    float2 a6 = fb[PHI(base + 6*Q)], a7 = fb[PHI(base + 7*Q)];
    const float R = 0.70710678118654752f;
    float2 u2, u4, u1c1, u1c3;
    if (S == 0) {
        u1 = make_float2(1.f, 0.f); u2 = u1; u4 = u1;
        u1c1 = make_float2( R,  R); u1c3 = make_float2(-R,  R);
    } else {
        u2 = cmulf(u1, u1); u4 = cmulf(u2, u2);
        u1c1 = cmulf(u1, make_float2( R,  R));
        u1c3 = cmulf(u1, make_float2(-R,  R));
    }
    float2 m;
    // stage S (half Q)
    m = cmulf(a1, u4); float2 t0 = cadd(a0,m), t1 = csub(a0,m);
    m = cmulf(a3, u4); float2 t2 = cadd(a2,m), t3 = csub(a2,m);
    m = cmulf(a5, u4); float2 t4 = cadd(a4,m), t5 = csub(a4,m);
    m = cmulf(a7, u4); float2 t6 = cadd(a6,m), t7 = csub(a6,m);
    // stage S+1 (half 2Q)
    m = cmulf(t2, u2);          float2 e0 = cadd(t0,m), e2 = csub(t0,m);
    m = mulposi(cmulf(t3, u2)); float2 e1 = cadd(t1,m), e3 = csub(t1,m);
    m = cmulf(t6, u2);          float2 e4 = cadd(t4,m), e6 = csub(t4,m);
    m = mulposi(cmulf(t7, u2)); float2 e5 = cadd(t5,m), e7 = csub(t5,m);
    // stage S+2 (half 4Q)
    m = cmulf(e4, u1);          fb[PHI(base      )] = cadd(e0,m); fb[PHI(base + 4*Q)] = csub(e0,m);
    m = cmulf(e5, u1c1);        fb[PHI(base +   Q)] = cadd(e1,m); fb[PHI(base + 5*Q)] = csub(e1,m);
    m = mulposi(cmulf(e6, u1)); fb[PHI(base + 2*Q)] = cadd(e2,m); fb[PHI(base + 6*Q)] = csub(e2,m);
    m = cmulf(e7, u1c3);        fb[PHI(base + 3*Q)] = cadd(e3,m); fb[PHI(base + 7*Q)] = csub(e3,m);
}

template<int S>
__device__ __forceinline__ void fwd8_auto(float2* fb, int tt){
    float ang = -W4096 * (float)((tt & ((1 << (S-2)) - 1)) << (11 - S));
    float2 w1; __sincosf(ang, &w1.y, &w1.x);
    fwd8<S>(fb, tt, w1);
}

// full circular convolution for 512-thread blocks; result scaled by 4096
__device__ __forceinline__ void conv_fft(float2* fb, const float2* __restrict__ G, int tid,
                                         float2 t11, float2 t8, float2 t5){
    __syncthreads();                       // fill visible
    fwd8<11>(fb, tid, t11); __syncthreads();
    fwd8<8 >(fb, tid, t8);  __syncthreads();
    fwd8<5 >(fb, tid, t5);  __syncthreads();
    fwd8<2 >(fb, tid, make_float2(1.f, 0.f)); __syncthreads();
    #pragma unroll
    for (int k = 0; k < 8; ++k){ int i = tid + k*512; fb[PHI(i)] = cmulf(fb[PHI(i)], G[i]); }
    __syncthreads();
    inv8<0>(fb, tid, make_float2(1.f, 0.f));        __syncthreads();
    inv8<3>(fb, tid, make_float2(t5.x,  -t5.y));    __syncthreads();
    inv8<6>(fb, tid, make_float2(t8.x,  -t8.y));    __syncthreads();
    inv8<9>(fb, tid, make_float2(t11.x, -t11.y));   __syncthreads();
}

// ---------------- block-wide sum reduce (512 threads = 8 waves), result to all
__device__ float block_reduce8(float v, volatile float* scratch) {
    int lane = threadIdx.x & 63;
    int wid  = threadIdx.x >> 6;
    #pragma unroll
    for (int off = 32; off > 0; off >>= 1) v += __shfl_down(v, off, 64);
    if (lane == 0) scratch[wid] = v;
    __syncthreads();
    if (wid == 0) {
        float s = (lane < 8) ? scratch[lane] : 0.0f;
        #pragma unroll
        for (int off = 4; off > 0; off >>= 1) s += __shfl_down(s, off, 64);
        if (lane == 0) scratch[16] = s;
    }
    __syncthreads();
    return scratch[16];
}

// ---------------- K1: one wave per output column; no atomics, no memset
__global__ __launch_bounds__(256) void k_prep(const float* __restrict__ x, const float* __restrict__ y,
                                              float2* __restrict__ d_v, float2* __restrict__ d_rhs){
    int gw = (blockIdx.x * 256 + threadIdx.x) >> 6;
    int lane = threadIdx.x & 63;
    if (gw >= 3073 + MN) return;
    bool is_v = gw < 3073;
    float pk = is_v ? (float)(gw - 1536) : (float)(gw - 3073 - 768);
    float sx = 0.f, sy = 0.f;
    if (is_v){
        for (int j = 0; j < 256; ++j){
            int n = j*64 + lane;
            float ph = CW * (x[n] * pk);
            float s, c; __sincosf(ph, &s, &c);
            sx += c; sy += s;
        }
    } else {
        for (int j = 0; j < 256; ++j){
            int n = j*64 + lane;
            float yv = y[n];
            float ph = CW * (x[n] * pk);
            float s, c; __sincosf(ph, &s, &c);
            sx += c*yv; sy -= s*yv;
        }
    }
    #pragma unroll
    for (int off = 32; off > 0; off >>= 1){
        sx += __shfl_down(sx, off, 64);
        sy += __shfl_down(sy, off, 64);
    }
    if (lane == 0){
        if (is_v) d_v[gw] = make_float2(sx, sy);
        else      d_rhs[gw - 3073] = make_float2(sx, sy);
    }
}

// ---------------- K2: G = FFT4096(g) in fused-radix-8 scrambled order
__global__ __launch_bounds__(1024) void k_buildG(const float2* __restrict__ d_v,
                                                 float2* __restrict__ d_G) {
    __shared__ float2 fb[FBN];
    int tid = threadIdx.x;
    #pragma unroll
    for (int k = 0; k < 4; ++k){
        int i = tid + k*1024;
        float2 val = make_float2(0.f, 0.f);
        if (i == 0)            val = d_v[1536];
        else if (i <= 1536)    val = d_v[1536 - i];
        else if (i >= 2560)    val = d_v[5632 - i];   // v_{i-4096}
        fb[PHI(i)] = val;
    }
    __syncthreads();
    if (tid < 512) fwd8_auto<11>(fb, tid); __syncthreads();
    if (tid < 512) fwd8_auto<8 >(fb, tid); __syncthreads();
    if (tid < 512) fwd8_auto<5 >(fb, tid); __syncthreads();
    if (tid < 512) fwd8_auto<2 >(fb, tid); __syncthreads();
    #pragma unroll
    for (int k = 0; k < 4; ++k){ int i = tid + k*1024; d_G[i] = fb[PHI(i)]; }
}

// ---------------- K3: blocks 0..63 = Lanczos per probe; block 64 = CG.
// 512 threads; thread t owns slots j = t + s*512, s=0..3 (slot 3 live only for t==0).
__global__ __launch_bounds__(512, 2) void k_solve(
    const float2* __restrict__ d_G, const float2* __restrict__ d_rhs,
    const float* __restrict__ d_z, float2* __restrict__ d_wb,
    float* __restrict__ d_al, float* __restrict__ d_be, float* __restrict__ d_nz2)
{
    __shared__ float2 fb[FBN];
    __shared__ float  red[17];
    int tid = threadIdx.x;
    int b = blockIdx.x;
    // per-thread loop-invariant twiddles (inverse = conj)
    float2 t11, t8, t5;
    { float a = -W4096 * (float)(tid & 511);        __sincosf(a, &t11.y, &t11.x); }
    { float a = -W4096 * (float)((tid & 63) << 3);  __sincosf(a, &t8.y,  &t8.x ); }
    { float a = -W4096 * (float)((tid & 7)  << 6);  __sincosf(a, &t5.y,  &t5.x ); }
    bool on3 = (tid == 0);
    float w[4];
    w[0] = ws_at(tid); w[1] = ws_at(tid + 512); w[2] = ws_at(tid + 1024);
    w[3] = on3 ? ws_at(1536) : 0.f;

    if (b < 64) {
        // ---------- Lanczos
        float2 q[4], qp[4];
        float part = 0.f;
        #pragma unroll
        for (int s = 0; s < 4; ++s){
            int j = tid + s*512;
            float sv = 0.f;
            if (s < 3 || on3){
                float zv = d_z[b*MN + j];
                sv = (zv > 0.f) ? 1.f : ((zv < 0.f) ? -1.f : 0.f);
            }
            q[s] = make_float2(sv, 0.f);
            qp[s] = make_float2(0.f, 0.f);
            part += sv * sv;
        }
        float nz2 = block_reduce8(part, red);
        if (tid == 0) d_nz2[b] = nz2;
        float qs = 1.0f / sqrtf(nz2);
        #pragma unroll
        for (int s = 0; s < 4; ++s){ q[s].x *= qs; q[s].y *= qs; }
        float bp = 0.f;
        float cf[4];
        #pragma unroll
        for (int s = 0; s < 4; ++s) cf[s] = w[s] * (10.0f / 4096.0f);
        for (int step = 0; step < 50; ++step) {
            #pragma unroll
            for (int s = 0; s < 4; ++s)
                fb[PHI(tid + s*512)] = make_float2(w[s]*q[s].x, w[s]*q[s].y);
            #pragma unroll
            for (int s = 4; s < 8; ++s)
                fb[PHI(tid + s*512)] = make_float2(0.f, 0.f);
            conv_fft(fb, d_G, tid, t11, t8, t5);
            float2 v[4];
            part = 0.f;
            #pragma unroll
            for (int s = 0; s < 4; ++s){
                float2 cv = (s < 3 || on3) ? fb[PHI(tid + s*512)] : make_float2(0.f, 0.f);
                v[s] = make_float2(q[s].x + cf[s]*cv.x - bp*qp[s].x,
                                   q[s].y + cf[s]*cv.y - bp*qp[s].y);
                part += q[s].x*v[s].x + q[s].y*v[s].y;
            }
            float alpha = block_reduce8(part, red);
            part = 0.f;
            #pragma unroll
            for (int s = 0; s < 4; ++s){
                v[s].x -= alpha*q[s].x; v[s].y -= alpha*q[s].y;
                part += v[s].x*v[s].x + v[s].y*v[s].y;
            }
            float nv = block_reduce8(part, red);
            float beta = sqrtf(nv);
            if (tid == 0) { d_al[b*50 + step] = alpha; d_be[b*50 + step] = beta; }
            float binv = 1.0f / fmaxf(beta, 1e-12f);
            #pragma unroll
            for (int s = 0; s < 4; ++s){
                qp[s] = q[s];
                q[s] = make_float2(v[s].x*binv, v[s].y*binv);
            }
            bp = beta;
        }
    } else {
        // ---------- CG
        float2 r[4], p[4], xx[4];
        float part = 0.f;
        #pragma unroll
        for (int s = 0; s < 4; ++s){
            int j = tid + s*512;
            float2 bj = make_float2(0.f, 0.f);
            if (s < 3 || on3){
                float2 rr = d_rhs[j];
                bj = make_float2(w[s]*rr.x, w[s]*rr.y);
            }
            r[s] = bj; p[s] = bj; xx[s] = make_float2(0.f, 0.f);
            part += bj.x*bj.x + bj.y*bj.y;
        }
        float rs = block_reduce8(part, red);
        float cf[4];
        #pragma unroll
        for (int s = 0; s < 4; ++s) cf[s] = w[s] * (1.0f / 4096.0f);
        for (int it = 0; it < 50; ++it) {
            #pragma unroll
            for (int s = 0; s < 4; ++s)
                fb[PHI(tid + s*512)] = make_float2(w[s]*p[s].x, w[s]*p[s].y);
            #pragma unroll
            for (int s = 4; s < 8; ++s)
                fb[PHI(tid + s*512)] = make_float2(0.f, 0.f);
            conv_fft(fb, d_G, tid, t11, t8, t5);
            float2 ap[4];
            part = 0.f;
            #pragma unroll
            for (int s = 0; s < 4; ++s){
                float2 cv = (s < 3 || on3) ? fb[PHI(tid + s*512)] : make_float2(0.f, 0.f);
                ap[s] = make_float2(cf[s]*cv.x + 0.1f*p[s].x, cf[s]*cv.y + 0.1f*p[s].y);
                part += p[s].x*ap[s].x + p[s].y*ap[s].y;
            }
            float pAp = block_reduce8(part, red);
            float a = rs / pAp;
            part = 0.f;
            #pragma unroll
            for (int s = 0; s < 4; ++s){
                xx[s].x += a*p[s].x; xx[s].y += a*p[s].y;
                r[s].x -= a*ap[s].x; r[s].y -= a*ap[s].y;
                part += r[s].x*r[s].x + r[s].y*r[s].y;
            }
            float rsn = block_reduce8(part, red);
            float sc = rsn / rs;
            #pragma unroll
            for (int s = 0; s < 4; ++s)
                p[s] = make_float2(r[s].x + sc*p[s].x, r[s].y + sc*p[s].y);
            rs = rsn;
        }
        #pragma unroll
        for (int s = 0; s < 4; ++s){
            if (s < 3 || on3)
                d_wb[tid + s*512] = make_float2(w[s]*xx[s].x, w[s]*xx[s].y);
        }
    }
}

// ---------------- K4: SLQ quadrature via Sturm bisection + Christoffel weights
__global__ __launch_bounds__(64) void k_slq(const float* __restrict__ d_al,
                                            const float* __restrict__ d_be,
                                            const float* __restrict__ d_nz2,
                                            float* __restrict__ d_quad) {
    __shared__ float a[50], e[50], e2[50];
    int b = blockIdx.x, t = threadIdx.x;
    if (t < 50) {
        a[t] = d_al[b*50 + t];
        float bv = (t < 49) ? d_be[b*50 + t] : 0.0f;
        e[t] = bv; e2[t] = bv * bv;
    }
    __syncthreads();
    float quad = 0.0f;
    if (t < 50) {
        float lo = 3.4e38f, hi = -3.4e38f;
        for (int i = 0; i < 50; ++i) {
            float r = ((i > 0) ? fabsf(e[i-1]) : 0.0f) + ((i < 49) ? fabsf(e[i]) : 0.0f);
            lo = fminf(lo, a[i] - r);
            hi = fmaxf(hi, a[i] + r);
        }
        for (int it = 0; it < 46; ++it) {
            float mid = 0.5f * (lo + hi);
            int cnt = 0;
            float q = a[0] - mid;
            if (q < 0.0f) cnt++;
            #pragma unroll 10
            for (int k = 1; k < 50; ++k) {
                float dnm = q;
                if (fabsf(dnm) < 1e-30f) dnm = (dnm < 0.0f) ? -1e-30f : 1e-30f;
                q = (a[k] - mid) - e2[k-1] / dnm;
                if (q < 0.0f) cnt++;
            }
            if (cnt > t) hi = mid; else lo = mid;
        }
        float lam = 0.5f * (lo + hi);
        float pm = 0.0f, pc = 1.0f, s = 1.0f, bprev = 0.0f;
        for (int k = 0; k < 49; ++k) {
            float bk = fmaxf(e[k], 1e-30f);
            float pn = ((lam - a[k]) * pc - bprev * pm) / bk;
            pn = fminf(fmaxf(pn, -1e18f), 1e18f);
            s += pn * pn;
            pm = pc; pc = pn; bprev = bk;
        }
        float w = 1.0f / s;
        quad = w * logf(fmaxf(lam, 1e-18f));
    }
    #pragma unroll
    for (int off = 32; off > 0; off >>= 1) quad += __shfl_down(quad, off, 64);
    if (t == 0) d_quad[b] = quad * d_nz2[b];
}

// ---------------- K5: fused mean (blocks 0..63) + t1 partials (blocks 64..127)
__global__ __launch_bounds__(256) void k_post(const float* __restrict__ x, const float* __restrict__ y,
                                              const float* __restrict__ xn, const float2* __restrict__ d_wb,
                                              float* __restrict__ out, float* __restrict__ d_t1p) {
    __shared__ float red4[4];
    int b = blockIdx.x, tid = threadIdx.x;
    if (b < 64) {
        int row = b*64 + (tid >> 2);
        int sub = tid & 3;
        float xv = xn[row];
        float acc = 0.f;
        for (int k = sub; k < MN; k += 4) {
            float ph = CW * (xv * (float)(k - 768));
            float s, c; __sincosf(ph, &s, &c);
            float2 w = d_wb[k];
            acc += c * w.x - s * w.y;
        }
        acc += __shfl_down(acc, 2, 4);
        acc += __shfl_down(acc, 1, 4);
        if (sub == 0) out[row] = acc;
    } else {
        int n = (b - 64)*256 + tid;
        float xv = x[n], yv = y[n];
        float acc = 0.f;
        for (int k = 0; k < MN; ++k) {
            float ph = CW * (xv * (float)(k - 768));
            float s, c; __sincosf(ph, &s, &c);
            float2 w = d_wb[k];
            acc += c * w.x - s * w.y;
        }
        float contrib = yv * (yv - acc) * 10.0f;
        #pragma unroll
        for (int off = 32; off > 0; off >>= 1) contrib += __shfl_down(contrib, off, 64);
        if ((tid & 63) == 0) red4[tid >> 6] = contrib;
        __syncthreads();
        if (tid == 0) d_t1p[b - 64] = red4[0] + red4[1] + red4[2] + red4[3];
    }
}

// ---------------- K6: lml
__global__ __launch_bounds__(64) void k_final(const float* __restrict__ d_t1p,
                                              const float* __restrict__ d_quad,
                                              float* __restrict__ out) {
    int t = threadIdx.x;
    float t1 = d_t1p[t];
    float q  = d_quad[t];
    #pragma unroll
    for (int off = 32; off > 0; off >>= 1) {
        t1 += __shfl_down(t1, off, 64);
        q  += __shfl_down(q,  off, 64);
    }
    if (t == 0) {
        float ld = q / 64.0f - 37725.5542f;           // + N*log(sigma^2)
        out[4096] = -0.5f * t1 - 0.5f * ld - 15055.8889f; // - 0.5*N*log(2pi)
    }
}

extern "C" void kernel_launch(void* const* d_in, const int* in_sizes, int n_in,
                              void* d_out, int out_size, void* d_ws, size_t ws_size,
                              hipStream_t stream) {
    const float* d_x  = (const float*)d_in[0];
    const float* d_y  = (const float*)d_in[1];
    const float* d_xn = (const float*)d_in[2];
    const float* d_z  = (const float*)d_in[3];
    float* out = (float*)d_out;
    char* w = (char*)d_ws;
    float2* d_v   = (float2*)(w + 0);       // 3073 c64
    float2* d_rhs = (float2*)(w + 24832);   // 1537 c64
    float2* d_G   = (float2*)(w + 37376);   // 4096 c64
    float2* d_wb  = (float2*)(w + 70144);   // 1537 c64
    float*  d_al  = (float*) (w + 82688);   // 64x50
    float*  d_be  = (float*) (w + 95488);   // 64x50
    float*  d_nz2 = (float*) (w + 108288);  // 64
    float*  d_quad= (float*) (w + 108544);  // 64
    float*  d_t1p = (float*) (w + 108800);  // 64

    k_prep  <<<1153, 256, 0, stream>>>(d_x, d_y, d_v, d_rhs);
    k_buildG<<<1, 1024, 0, stream>>>(d_v, d_G);
    k_solve <<<65, 512, 0, stream>>>(d_G, d_rhs, d_z, d_wb, d_al, d_be, d_nz2);
    k_slq   <<<64, 64, 0, stream>>>(d_al, d_be, d_nz2, d_quad);
    k_post  <<<128, 256, 0, stream>>>(d_x, d_y, d_xn, d_wb, out, d_t1p);
    k_final <<<1, 64, 0, stream>>>(d_t1p, d_quad, out);
}

// Round 5
// 513.288 us; speedup vs baseline: 4.3801x; 1.2153x over previous
//
#include <hip/hip_runtime.h>
#include <hip/hip_cooperative_groups.h>
#include <math.h>

namespace cg = cooperative_groups;

#define MN 1537          // M_NODES
#define NFFT 4096
#define FBN (NFFT + NFFT/8)   // padded LDS size (float2 units)
#define CW 0.06283185307179587f      // 2*pi*h
#define W4096 1.5339807878856412e-3f // 2*pi/4096

__device__ __forceinline__ float2 cmulf(float2 a, float2 b) {
    return make_float2(a.x*b.x - a.y*b.y, a.x*b.y + a.y*b.x);
}
__device__ __forceinline__ float2 cadd(float2 a, float2 b){ return make_float2(a.x+b.x, a.y+b.y); }
__device__ __forceinline__ float2 csub(float2 a, float2 b){ return make_float2(a.x-b.x, a.y-b.y); }
__device__ __forceinline__ float2 mulnegi(float2 z){ return make_float2(z.y, -z.x); }  // z * (-i)
__device__ __forceinline__ float2 mulposi(float2 z){ return make_float2(-z.y, z.x); }  // z * (+i)
__device__ __forceinline__ float2 cconj(float2 z){ return make_float2(z.x, -z.y); }
__device__ __forceinline__ int PHI(int i){ return i + (i >> 3); }  // bank-conflict pad

__device__ __forceinline__ float ws_at(int k) {
    float xi = 0.01f * (float)(k - 768);
    float t  = 0.31415926535897931f * xi;      // pi*ell*xi
    float S  = 0.25066282746310002f * expf(-2.0f * t * t); // sqrt(2pi)*ell
    return sqrtf(0.01f * S);
}

// ---------------- radix-8 fused stages (3 radix-2 stages in registers, in place)
template<int S>
__device__ __forceinline__ void fwd8(float2* fb, int tt, float2 w1){
    const int Q = 1 << (S-2);
    const int p = tt & (Q-1);
    const int g = tt >> (S-2);
    const int base = (g << (S+1)) + p;
    float2 a0 = fb[PHI(base      )], a1 = fb[PHI(base +   Q)];
    float2 a2 = fb[PHI(base + 2*Q)], a3 = fb[PHI(base + 3*Q)];
    float2 a4 = fb[PHI(base + 4*Q)], a5 = fb[PHI(base + 5*Q)];
    float2 a6 = fb[PHI(base + 6*Q)], a7 = fb[PHI(base + 7*Q)];
    const float R = 0.70710678118654752f;
    float2 w2, w4, w1c1, w1c3;
    if (S == 2) {
        w1 = make_float2(1.f, 0.f); w2 = w1; w4 = w1;
        w1c1 = make_float2( R, -R); w1c3 = make_float2(-R, -R);
    } else {
        w2 = cmulf(w1, w1); w4 = cmulf(w2, w2);
        w1c1 = cmulf(w1, make_float2( R, -R));
        w1c3 = cmulf(w1, make_float2(-R, -R));
    }
    float2 b0 = cadd(a0,a4), b1 = cadd(a1,a5), b2 = cadd(a2,a6), b3 = cadd(a3,a7);
    float2 b4 = cmulf(csub(a0,a4), w1);
    float2 b5 = cmulf(csub(a1,a5), w1c1);
    float2 b6 = mulnegi(cmulf(csub(a2,a6), w1));
    float2 b7 = cmulf(csub(a3,a7), w1c3);
    float2 c0 = cadd(b0,b2), c2 = cmulf(csub(b0,b2), w2);
    float2 c1 = cadd(b1,b3), c3 = mulnegi(cmulf(csub(b1,b3), w2));
    float2 c4 = cadd(b4,b6), c6 = cmulf(csub(b4,b6), w2);
    float2 c5 = cadd(b5,b7), c7 = mulnegi(cmulf(csub(b5,b7), w2));
    fb[PHI(base      )] = cadd(c0,c1);
    fb[PHI(base +   Q)] = cmulf(csub(c0,c1), w4);
    fb[PHI(base + 2*Q)] = cadd(c2,c3);
    fb[PHI(base + 3*Q)] = cmulf(csub(c2,c3), w4);
    fb[PHI(base + 4*Q)] = cadd(c4,c5);
    fb[PHI(base + 5*Q)] = cmulf(csub(c4,c5), w4);
    fb[PHI(base + 6*Q)] = cadd(c6,c7);
    fb[PHI(base + 7*Q)] = cmulf(csub(c6,c7), w4);
}

template<int S>
__device__ __forceinline__ void inv8(float2* fb, int tt, float2 u1){
    const int Q = 1 << S;
    const int p = tt & (Q-1);
    const int g = tt >> S;
    const int base = (g << (S+3)) + p;
    float2 a0 = fb[PHI(base      )], a1 = fb[PHI(base +   Q)];
    float2 a2 = fb[PHI(base + 2*Q)], a3 = fb[PHI(base + 3*Q)];
    float2 a4 = fb[PHI(base + 4*Q)], a5 = fb[PHI(base + 5*Q)];
    float2 a6 = fb[PHI(base + 6*Q)], a7 = fb[PHI(base + 7*Q)];
    const float R = 0.70710678118654752f;
    float2 u2, u4, u1c1, u1c3;
    if (S == 0) {
        u1 = make_float2(1.f, 0.f); u2 = u1; u4 = u1;
        u1c1 = make_float2( R,  R); u1c3 = make_float2(-R,  R);
    } else {
        u2 = cmulf(u1, u1); u4 = cmulf(u2, u2);
        u1c1 = cmulf(u1, make_float2( R,  R));
        u1c3 = cmulf(u1, make_float2(-R,  R));
    }
    float2 m;
    m = cmulf(a1, u4); float2 t0 = cadd(a0,m), t1 = csub(a0,m);
    m = cmulf(a3, u4); float2 t2 = cadd(a2,m), t3 = csub(a2,m);
    m = cmulf(a5, u4); float2 t4 = cadd(a4,m), t5 = csub(a4,m);
    m = cmulf(a7, u4); float2 t6 = cadd(a6,m), t7 = csub(a6,m);
    m = cmulf(t2, u2);          float2 e0 = cadd(t0,m), e2 = csub(t0,m);
    m = mulposi(cmulf(t3, u2)); float2 e1 = cadd(t1,m), e3 = csub(t1,m);
    m = cmulf(t6, u2);          float2 e4 = cadd(t4,m), e6 = csub(t4,m);
    m = mulposi(cmulf(t7, u2)); float2 e5 = cadd(t5,m), e7 = csub(t5,m);
    m = cmulf(e4, u1);          fb[PHI(base      )] = cadd(e0,m); fb[PHI(base + 4*Q)] = csub(e0,m);
    m = cmulf(e5, u1c1);        fb[PHI(base +   Q)] = cadd(e1,m); fb[PHI(base + 5*Q)] = csub(e1,m);
    m = mulposi(cmulf(e6, u1)); fb[PHI(base + 2*Q)] = cadd(e2,m); fb[PHI(base + 6*Q)] = csub(e2,m);
    m = cmulf(e7, u1c3);        fb[PHI(base + 3*Q)] = cadd(e3,m); fb[PHI(base + 7*Q)] = csub(e3,m);
}

// stage-11 triple with inputs from registers (slots tid+s*512; s>=4 are zero)
__device__ __forceinline__ void fwd8_first(float2* fb, int tt, float2 w1, const float2* in){
    const float R = 0.70710678118654752f;
    float2 w2 = cmulf(w1, w1), w4 = cmulf(w2, w2);
    float2 w1c1 = cmulf(w1, make_float2( R, -R));
    float2 w1c3 = cmulf(w1, make_float2(-R, -R));
    float2 b0 = in[0], b1 = in[1], b2 = in[2], b3 = in[3];
    float2 b4 = cmulf(in[0], w1);
    float2 b5 = cmulf(in[1], w1c1);
    float2 b6 = mulnegi(cmulf(in[2], w1));
    float2 b7 = cmulf(in[3], w1c3);
    float2 c0 = cadd(b0,b2), c2 = cmulf(csub(b0,b2), w2);
    float2 c1 = cadd(b1,b3), c3 = mulnegi(cmulf(csub(b1,b3), w2));
    float2 c4 = cadd(b4,b6), c6 = cmulf(csub(b4,b6), w2);
    float2 c5 = cadd(b5,b7), c7 = mulnegi(cmulf(csub(b5,b7), w2));
    fb[PHI(tt       )] = cadd(c0,c1);
    fb[PHI(tt +  512)] = cmulf(csub(c0,c1), w4);
    fb[PHI(tt + 1024)] = cadd(c2,c3);
    fb[PHI(tt + 1536)] = cmulf(csub(c2,c3), w4);
    fb[PHI(tt + 2048)] = cadd(c4,c5);
    fb[PHI(tt + 2560)] = cmulf(csub(c4,c5), w4);
    fb[PHI(tt + 3072)] = cadd(c6,c7);
    fb[PHI(tt + 3584)] = cmulf(csub(c6,c7), w4);
}

// inverse stage-9 triple returning only slots tid+s*512 (s=0..3) in registers
__device__ __forceinline__ void inv8_last(const float2* fb, int tt, float2 u1, float2* outv){
    const float R = 0.70710678118654752f;
    float2 u2 = cmulf(u1, u1), u4 = cmulf(u2, u2);
    float2 u1c1 = cmulf(u1, make_float2( R,  R));
    float2 u1c3 = cmulf(u1, make_float2(-R,  R));
    float2 a0 = fb[PHI(tt       )], a1 = fb[PHI(tt +  512)];
    float2 a2 = fb[PHI(tt + 1024)], a3 = fb[PHI(tt + 1536)];
    float2 a4 = fb[PHI(tt + 2048)], a5 = fb[PHI(tt + 2560)];
    float2 a6 = fb[PHI(tt + 3072)], a7 = fb[PHI(tt + 3584)];
    float2 m;
    m = cmulf(a1, u4); float2 t0 = cadd(a0,m), t1 = csub(a0,m);
    m = cmulf(a3, u4); float2 t2 = cadd(a2,m), t3 = csub(a2,m);
    m = cmulf(a5, u4); float2 t4 = cadd(a4,m), t5 = csub(a4,m);
    m = cmulf(a7, u4); float2 t6 = cadd(a6,m), t7 = csub(a6,m);
    m = cmulf(t2, u2);          float2 e0 = cadd(t0,m), e2 = csub(t0,m);
    m = mulposi(cmulf(t3, u2)); float2 e1 = cadd(t1,m), e3 = csub(t1,m);
    m = cmulf(t6, u2);          float2 e4 = cadd(t4,m), e6 = csub(t4,m);
    m = mulposi(cmulf(t7, u2)); float2 e5 = cadd(t5,m), e7 = csub(t5,m);
    outv[0] = cadd(e0, cmulf(e4, u1));
    outv[1] = cadd(e1, cmulf(e5, u1c1));
    outv[2] = cadd(e2, mulposi(cmulf(e6, u1)));
    outv[3] = cadd(e3, cmulf(e7, u1c3));
}

// circular convolution with kernel spectrum in registers g[8]; scaled by 4096
__device__ __forceinline__ void conv_fft(float2* fb, const float2* g, int tid,
                                         float2 t11, float2 t8, float2 t5,
                                         const float2* in, float2* outv){
    __syncthreads();                       // prior reads of fb done
    fwd8_first(fb, tid, t11, in); __syncthreads();
    fwd8<8>(fb, tid, t8);  __syncthreads();
    fwd8<5>(fb, tid, t5);  __syncthreads();
    fwd8<2>(fb, tid, make_float2(1.f, 0.f)); __syncthreads();
    #pragma unroll
    for (int k = 0; k < 8; ++k){ int i = PHI(tid + k*512); fb[i] = cmulf(fb[i], g[k]); }
    __syncthreads();
    inv8<0>(fb, tid, make_float2(1.f, 0.f)); __syncthreads();
    inv8<3>(fb, tid, cconj(t5)); __syncthreads();
    inv8<6>(fb, tid, cconj(t8)); __syncthreads();
    inv8_last(fb, tid, cconj(t11), outv);
}

// block-wide sum reduce (512 threads = 8 waves), result to all
__device__ float block_reduce8(float v, volatile float* scratch) {
    int lane = threadIdx.x & 63;
    int wid  = threadIdx.x >> 6;
    #pragma unroll
    for (int off = 32; off > 0; off >>= 1) v += __shfl_down(v, off, 64);
    if (lane == 0) scratch[wid] = v;
    __syncthreads();
    if (wid == 0) {
        float s = (lane < 8) ? scratch[lane] : 0.0f;
        #pragma unroll
        for (int off = 4; off > 0; off >>= 1) s += __shfl_down(s, off, 64);
        if (lane == 0) scratch[16] = s;
    }
    __syncthreads();
    return scratch[16];
}

// ======================= the cooperative mega-kernel =======================
__global__ __launch_bounds__(512) __attribute__((amdgpu_waves_per_eu(2, 2)))
void mega(const float* __restrict__ x, const float* __restrict__ y,
          const float* __restrict__ xn, const float* __restrict__ z,
          float* __restrict__ out,
          float2* __restrict__ d_v, float2* __restrict__ d_rhs, float2* __restrict__ d_wb,
          float* __restrict__ d_al, float* __restrict__ d_be, float* __restrict__ d_nz2,
          float* __restrict__ d_quad, float* __restrict__ d_t1p)
{
    __shared__ float2 fb[FBN];
    __shared__ float  red[17];
    cg::grid_group grid = cg::this_grid();
    const int b = blockIdx.x, tid = threadIdx.x;
    const int wid = tid >> 6, lane = tid & 63;

    // ---------------- phase P: build v (3073 cols) and rhs (1537 cols), one wave per col
    for (int c = b*8 + wid; c < 3073 + MN; c += 2048) {
        bool is_v = c < 3073;
        float pk = is_v ? (float)(c - 1536) : (float)(c - 3073 - 768);
        float sx = 0.f, sy = 0.f;
        if (is_v){
            for (int j = 0; j < 256; ++j){
                float ph = CW * (x[j*64 + lane] * pk);
                float s, cc; __sincosf(ph, &s, &cc);
                sx += cc; sy += s;
            }
        } else {
            for (int j = 0; j < 256; ++j){
                int n = j*64 + lane;
                float yv = y[n];
                float ph = CW * (x[n] * pk);
                float s, cc; __sincosf(ph, &s, &cc);
                sx += cc*yv; sy -= s*yv;
            }
        }
        #pragma unroll
        for (int off = 32; off > 0; off >>= 1){
            sx += __shfl_down(sx, off, 64);
            sy += __shfl_down(sy, off, 64);
        }
        if (lane == 0){
            if (is_v) d_v[c] = make_float2(sx, sy);
            else      d_rhs[c - 3073] = make_float2(sx, sy);
        }
    }
    grid.sync();

    // ---------------- phase S: blocks 0..63 Lanczos, block 64 CG
    if (b < 65) {
        float2 t11, t8, t5;
        { float a = -W4096 * (float)tid;               __sincosf(a, &t11.y, &t11.x); }
        { float a = -W4096 * (float)((tid & 63) << 3); __sincosf(a, &t8.y,  &t8.x ); }
        { float a = -W4096 * (float)((tid & 7)  << 6); __sincosf(a, &t5.y,  &t5.x ); }
        bool on3 = (tid == 0);
        float w[4];
        w[0] = ws_at(tid); w[1] = ws_at(tid + 512); w[2] = ws_at(tid + 1024);
        w[3] = on3 ? ws_at(1536) : 0.f;

        // build G into registers (each block independently; ~3 us)
        float2 g[8];
        #pragma unroll
        for (int k = 0; k < 8; ++k){
            int i = tid + k*512;
            float2 val = make_float2(0.f, 0.f);
            if (i == 0)            val = d_v[1536];
            else if (i <= 1536)    val = d_v[1536 - i];
            else if (i >= 2560)    val = d_v[5632 - i];
            fb[PHI(i)] = val;
        }
        __syncthreads();
        fwd8<11>(fb, tid, t11); __syncthreads();
        fwd8<8 >(fb, tid, t8);  __syncthreads();
        fwd8<5 >(fb, tid, t5);  __syncthreads();
        fwd8<2 >(fb, tid, make_float2(1.f, 0.f)); __syncthreads();
        #pragma unroll
        for (int k = 0; k < 8; ++k) g[k] = fb[PHI(tid + k*512)];

        float2 sin_[4], cv[4];
        if (b < 64) {
            // ---------- Lanczos
            float2 q[4], qp[4];
            float part = 0.f;
            #pragma unroll
            for (int s = 0; s < 4; ++s){
                float sv = 0.f;
                if (s < 3 || on3){
                    float zv = z[b*MN + tid + s*512];
                    sv = (zv > 0.f) ? 1.f : ((zv < 0.f) ? -1.f : 0.f);
                }
                q[s] = make_float2(sv, 0.f);
                qp[s] = make_float2(0.f, 0.f);
                part += sv * sv;
            }
            float nz2 = block_reduce8(part, red);
            if (tid == 0) d_nz2[b] = nz2;
            float qs = 1.0f / sqrtf(nz2);
            #pragma unroll
            for (int s = 0; s < 4; ++s){ q[s].x *= qs; q[s].y *= qs; }
            float bp = 0.f;
            float cf[4];
            #pragma unroll
            for (int s = 0; s < 4; ++s) cf[s] = w[s] * (10.0f / 4096.0f);
            for (int step = 0; step < 50; ++step) {
                #pragma unroll
                for (int s = 0; s < 4; ++s)
                    sin_[s] = make_float2(w[s]*q[s].x, w[s]*q[s].y);
                conv_fft(fb, g, tid, t11, t8, t5, sin_, cv);
                float2 v[4];
                part = 0.f;
                #pragma unroll
                for (int s = 0; s < 4; ++s){
                    v[s] = make_float2(q[s].x + cf[s]*cv[s].x - bp*qp[s].x,
                                       q[s].y + cf[s]*cv[s].y - bp*qp[s].y);
                    part += q[s].x*v[s].x + q[s].y*v[s].y;
                }
                float alpha = block_reduce8(part, red);
                part = 0.f;
                #pragma unroll
                for (int s = 0; s < 4; ++s){
                    v[s].x -= alpha*q[s].x; v[s].y -= alpha*q[s].y;
                    part += v[s].x*v[s].x + v[s].y*v[s].y;
                }
                float nv = block_reduce8(part, red);
                float beta = sqrtf(nv);
                if (tid == 0) { d_al[b*50 + step] = alpha; d_be[b*50 + step] = beta; }
                float binv = 1.0f / fmaxf(beta, 1e-12f);
                #pragma unroll
                for (int s = 0; s < 4; ++s){
                    qp[s] = q[s];
                    q[s] = make_float2(v[s].x*binv, v[s].y*binv);
                }
                bp = beta;
            }
        } else {
            // ---------- CG
            float2 r[4], p[4], xx[4];
            float part = 0.f;
            #pragma unroll
            for (int s = 0; s < 4; ++s){
                float2 bj = make_float2(0.f, 0.f);
                if (s < 3 || on3){
                    float2 rr = d_rhs[tid + s*512];
                    bj = make_float2(w[s]*rr.x, w[s]*rr.y);
                }
                r[s] = bj; p[s] = bj; xx[s] = make_float2(0.f, 0.f);
                part += bj.x*bj.x + bj.y*bj.y;
            }
            float rs = block_reduce8(part, red);
            float cf[4];
            #pragma unroll
            for (int s = 0; s < 4; ++s) cf[s] = w[s] * (1.0f / 4096.0f);
            for (int it = 0; it < 50; ++it) {
                #pragma unroll
                for (int s = 0; s < 4; ++s)
                    sin_[s] = make_float2(w[s]*p[s].x, w[s]*p[s].y);
                conv_fft(fb, g, tid, t11, t8, t5, sin_, cv);
                float2 ap[4];
                part = 0.f;
                #pragma unroll
                for (int s = 0; s < 4; ++s){
                    ap[s] = make_float2(cf[s]*cv[s].x + 0.1f*p[s].x,
                                        cf[s]*cv[s].y + 0.1f*p[s].y);
                    part += p[s].x*ap[s].x + p[s].y*ap[s].y;
                }
                float pAp = block_reduce8(part, red);
                float a = rs / pAp;
                part = 0.f;
                #pragma unroll
                for (int s = 0; s < 4; ++s){
                    xx[s].x += a*p[s].x; xx[s].y += a*p[s].y;
                    r[s].x -= a*ap[s].x; r[s].y -= a*ap[s].y;
                    part += r[s].x*r[s].x + r[s].y*r[s].y;
                }
                float rsn = block_reduce8(part, red);
                float sc = rsn / rs;
                #pragma unroll
                for (int s = 0; s < 4; ++s)
                    p[s] = make_float2(r[s].x + sc*p[s].x, r[s].y + sc*p[s].y);
                rs = rsn;
            }
            #pragma unroll
            for (int s = 0; s < 4; ++s){
                if (s < 3 || on3)
                    d_wb[tid + s*512] = make_float2(w[s]*xx[s].x, w[s]*xx[s].y);
            }
        }
    }
    grid.sync();

    // ---------------- phase T: slq (blocks 0-63) | mean (64-95) | t1 (96-223)
    if (b < 64) {
        if (tid < 64) {
            float* sa  = (float*)fb;       // a[64] | e[64] | e2[64]
            float* se  = sa + 64;
            float* se2 = sa + 128;
            int t = tid;
            if (t < 50) {
                sa[t] = d_al[b*50 + t];
                float bv = (t < 49) ? d_be[b*50 + t] : 0.0f;
                se[t] = bv; se2[t] = bv * bv;
            }
            float quad = 0.0f;
            if (t < 50) {
                float lo = 3.4e38f, hi = -3.4e38f;
                for (int i = 0; i < 50; ++i) {
                    float rr = ((i > 0) ? fabsf(se[i-1]) : 0.0f) + ((i < 49) ? fabsf(se[i]) : 0.0f);
                    lo = fminf(lo, sa[i] - rr);
                    hi = fmaxf(hi, sa[i] + rr);
                }
                for (int it = 0; it < 38; ++it) {
                    float mid = 0.5f * (lo + hi);
                    int cnt = 0;
                    float qq = sa[0] - mid;
                    cnt += (qq < 0.0f);
                    for (int k = 1; k < 50; ++k) {
                        float dnm = (fabsf(qq) < 1e-30f) ? ((qq < 0.0f) ? -1e-30f : 1e-30f) : qq;
                        qq = (sa[k] - mid) - se2[k-1] * __builtin_amdgcn_rcpf(dnm);
                        cnt += (qq < 0.0f);
                    }
                    if (cnt > t) hi = mid; else lo = mid;
                }
                float lam = 0.5f * (lo + hi);
                float pm = 0.0f, pc = 1.0f, s = 1.0f, bprev = 0.0f;
                for (int k = 0; k < 49; ++k) {
                    float bk = fmaxf(se[k], 1e-30f);
                    float pn = ((lam - sa[k]) * pc - bprev * pm) * __builtin_amdgcn_rcpf(bk);
                    pn = fminf(fmaxf(pn, -1e18f), 1e18f);
                    s += pn * pn;
                    pm = pc; pc = pn; bprev = bk;
                }
                quad = logf(fmaxf(lam, 1e-18f)) / s;
            }
            #pragma unroll
            for (int off = 32; off > 0; off >>= 1) quad += __shfl_down(quad, off, 64);
            if (t == 0) d_quad[b] = quad * d_nz2[b];
        }
    } else if (b < 96) {
        int row = (b - 64)*128 + (tid >> 2);
        int sub = tid & 3;
        float xv = xn[row];
        float acc = 0.f;
        for (int k = sub; k < MN; k += 4) {
            float ph = CW * (xv * (float)(k - 768));
            float s, c; __sincosf(ph, &s, &c);
            float2 ww = d_wb[k];
            acc += c * ww.x - s * ww.y;
        }
        acc += __shfl_down(acc, 2, 4);
        acc += __shfl_down(acc, 1, 4);
        if (sub == 0) out[row] = acc;
    } else if (b < 224) {
        int n = (b - 96)*128 + (tid >> 2);
        int sub = tid & 3;
        float xv = x[n], yv = y[n];
        float acc = 0.f;
        for (int k = sub; k < MN; k += 4) {
            float ph = CW * (xv * (float)(k - 768));
            float s, c; __sincosf(ph, &s, &c);
            float2 ww = d_wb[k];
            acc += c * ww.x - s * ww.y;
        }
        acc += __shfl_down(acc, 2, 4);
        acc += __shfl_down(acc, 1, 4);
        float contrib = (sub == 0) ? yv * (yv - acc) * 10.0f : 0.f;
        #pragma unroll
        for (int off = 32; off > 0; off >>= 1) contrib += __shfl_down(contrib, off, 64);
        if (lane == 0) red[wid] = contrib;
        __syncthreads();
        if (tid == 0) {
            float s = 0.f;
            #pragma unroll
            for (int i = 0; i < 8; ++i) s += red[i];
            d_t1p[b - 96] = s;
        }
    }
    grid.sync();

    // ---------------- final: lml
    if (b == 0 && tid < 64) {
        float qv = d_quad[tid];
        float t1 = d_t1p[tid] + d_t1p[tid + 64];
        #pragma unroll
        for (int off = 32; off > 0; off >>= 1) {
            qv += __shfl_down(qv, off, 64);
            t1 += __shfl_down(t1, off, 64);
        }
        if (tid == 0) {
            float ld = qv / 64.0f - 37725.5542f;              // + N*log(sigma^2)
            out[4096] = -0.5f * t1 - 0.5f * ld - 15055.8889f; // - 0.5*N*log(2pi)
        }
    }
}

extern "C" void kernel_launch(void* const* d_in, const int* in_sizes, int n_in,
                              void* d_out, int out_size, void* d_ws, size_t ws_size,
                              hipStream_t stream) {
    const float* d_x  = (const float*)d_in[0];
    const float* d_y  = (const float*)d_in[1];
    const float* d_xn = (const float*)d_in[2];
    const float* d_z  = (const float*)d_in[3];
    float* out = (float*)d_out;
    char* w = (char*)d_ws;
    float2* d_v   = (float2*)(w + 0);       // 3073 c64
    float2* d_rhs = (float2*)(w + 24832);   // 1537 c64
    float2* d_wb  = (float2*)(w + 37376);   // 1537 c64
    float*  d_al  = (float*)(w + 49920);    // 64x50
    float*  d_be  = (float*)(w + 62720);    // 64x50
    float*  d_nz2 = (float*)(w + 75520);    // 64
    float*  d_quad= (float*)(w + 75776);    // 64
    float*  d_t1p = (float*)(w + 76032);    // 128

    void* args[] = { (void*)&d_x, (void*)&d_y, (void*)&d_xn, (void*)&d_z, (void*)&out,
                     (void*)&d_v, (void*)&d_rhs, (void*)&d_wb, (void*)&d_al, (void*)&d_be,
                     (void*)&d_nz2, (void*)&d_quad, (void*)&d_t1p };
    hipLaunchCooperativeKernel((const void*)mega, dim3(256), dim3(512), args, 0, stream);
}

// Round 6
// 477.606 us; speedup vs baseline: 4.7074x; 1.0747x over previous
//
#include <hip/hip_runtime.h>
#include <hip/hip_cooperative_groups.h>
#include <math.h>

namespace cg = cooperative_groups;

#define MN 1537          // M_NODES
#define NFFT 4096
#define FBN (NFFT + NFFT/8 + NFFT/64)   // padded LDS size (float2 units) = 4672
#define CW 0.06283185307179587f      // 2*pi*h
#define W4096 1.5339807878856412e-3f // 2*pi/4096

__device__ __forceinline__ float2 cmulf(float2 a, float2 b) {
    return make_float2(a.x*b.x - a.y*b.y, a.x*b.y + a.y*b.x);
}
__device__ __forceinline__ float2 cadd(float2 a, float2 b){ return make_float2(a.x+b.x, a.y+b.y); }
__device__ __forceinline__ float2 csub(float2 a, float2 b){ return make_float2(a.x-b.x, a.y-b.y); }
__device__ __forceinline__ float2 mulnegi(float2 z){ return make_float2(z.y, -z.x); }  // z * (-i)
__device__ __forceinline__ float2 mulposi(float2 z){ return make_float2(-z.y, z.x); }  // z * (+i)
__device__ __forceinline__ float2 cconj(float2 z){ return make_float2(z.x, -z.y); }
// swizzle: uniform bank spread for strides {1,8,64,512} (b64 accesses)
__device__ __forceinline__ int PHI(int i){ return i + (i >> 3) + (i >> 6); }

__device__ __forceinline__ float ws_at(int k) {
    float xi = 0.01f * (float)(k - 768);
    float t  = 0.31415926535897931f * xi;      // pi*ell*xi
    float S  = 0.25066282746310002f * expf(-2.0f * t * t); // sqrt(2pi)*ell
    return sqrtf(0.01f * S);
}

// cached twiddle quintet for one fused stage-triple
struct Tw { float2 w1, w2, w4, c1, c3; };

__device__ __forceinline__ Tw make_tw(float ang){
    Tw t;
    __sincosf(ang, &t.w1.y, &t.w1.x);
    t.w2 = cmulf(t.w1, t.w1);
    t.w4 = cmulf(t.w2, t.w2);
    const float R = 0.70710678118654752f;
    t.c1 = cmulf(t.w1, make_float2( R, -R));   // w1 * e^{-i pi/4}
    t.c3 = cmulf(t.w1, make_float2(-R, -R));   // w1 * e^{-i 3pi/4}
    return t;
}

// ---------------- forward DIF triple (stages S, S-1, S-2), cached twiddles
template<int S>
__device__ __forceinline__ void fwd8c(float2* fb, int tt, const Tw& w){
    const int Q = 1 << (S-2);
    const int p = tt & (Q-1);
    const int g = tt >> (S-2);
    const int base = (g << (S+1)) + p;
    float2 a0 = fb[PHI(base      )], a1 = fb[PHI(base +   Q)];
    float2 a2 = fb[PHI(base + 2*Q)], a3 = fb[PHI(base + 3*Q)];
    float2 a4 = fb[PHI(base + 4*Q)], a5 = fb[PHI(base + 5*Q)];
    float2 a6 = fb[PHI(base + 6*Q)], a7 = fb[PHI(base + 7*Q)];
    float2 b0 = cadd(a0,a4), b1 = cadd(a1,a5), b2 = cadd(a2,a6), b3 = cadd(a3,a7);
    float2 b4 = cmulf(csub(a0,a4), w.w1);
    float2 b5 = cmulf(csub(a1,a5), w.c1);
    float2 b6 = mulnegi(cmulf(csub(a2,a6), w.w1));
    float2 b7 = cmulf(csub(a3,a7), w.c3);
    float2 c0 = cadd(b0,b2), c2 = cmulf(csub(b0,b2), w.w2);
    float2 c1 = cadd(b1,b3), c3 = mulnegi(cmulf(csub(b1,b3), w.w2));
    float2 c4 = cadd(b4,b6), c6 = cmulf(csub(b4,b6), w.w2);
    float2 c5 = cadd(b5,b7), c7 = mulnegi(cmulf(csub(b5,b7), w.w2));
    fb[PHI(base      )] = cadd(c0,c1);
    fb[PHI(base +   Q)] = cmulf(csub(c0,c1), w.w4);
    fb[PHI(base + 2*Q)] = cadd(c2,c3);
    fb[PHI(base + 3*Q)] = cmulf(csub(c2,c3), w.w4);
    fb[PHI(base + 4*Q)] = cadd(c4,c5);
    fb[PHI(base + 5*Q)] = cmulf(csub(c4,c5), w.w4);
    fb[PHI(base + 6*Q)] = cadd(c6,c7);
    fb[PHI(base + 7*Q)] = cmulf(csub(c6,c7), w.w4);
}

// ---------------- inverse DIT triple (stages S, S+1, S+2), twiddles = conj(cached)
template<int S>
__device__ __forceinline__ void inv8c(float2* fb, int tt, const Tw& w){
    const int Q = 1 << S;
    const int p = tt & (Q-1);
    const int g = tt >> S;
    const int base = (g << (S+3)) + p;
    float2 u1 = cconj(w.w1), u2 = cconj(w.w2), u4 = cconj(w.w4);
    float2 uc1 = cconj(w.c1), uc3 = cconj(w.c3);
    float2 a0 = fb[PHI(base      )], a1 = fb[PHI(base +   Q)];
    float2 a2 = fb[PHI(base + 2*Q)], a3 = fb[PHI(base + 3*Q)];
    float2 a4 = fb[PHI(base + 4*Q)], a5 = fb[PHI(base + 5*Q)];
    float2 a6 = fb[PHI(base + 6*Q)], a7 = fb[PHI(base + 7*Q)];
    float2 m;
    m = cmulf(a1, u4); float2 t0 = cadd(a0,m), t1 = csub(a0,m);
    m = cmulf(a3, u4); float2 t2 = cadd(a2,m), t3 = csub(a2,m);
    m = cmulf(a5, u4); float2 t4 = cadd(a4,m), t5 = csub(a4,m);
    m = cmulf(a7, u4); float2 t6 = cadd(a6,m), t7 = csub(a6,m);
    m = cmulf(t2, u2);          float2 e0 = cadd(t0,m), e2 = csub(t0,m);
    m = mulposi(cmulf(t3, u2)); float2 e1 = cadd(t1,m), e3 = csub(t1,m);
    m = cmulf(t6, u2);          float2 e4 = cadd(t4,m), e6 = csub(t4,m);
    m = mulposi(cmulf(t7, u2)); float2 e5 = cadd(t5,m), e7 = csub(t5,m);
    m = cmulf(e4, u1);          fb[PHI(base      )] = cadd(e0,m); fb[PHI(base + 4*Q)] = csub(e0,m);
    m = cmulf(e5, uc1);         fb[PHI(base +   Q)] = cadd(e1,m); fb[PHI(base + 5*Q)] = csub(e1,m);
    m = mulposi(cmulf(e6, u1)); fb[PHI(base + 2*Q)] = cadd(e2,m); fb[PHI(base + 6*Q)] = csub(e2,m);
    m = cmulf(e7, uc3);         fb[PHI(base + 3*Q)] = cadd(e3,m); fb[PHI(base + 7*Q)] = csub(e3,m);
}

// stage-11 triple, inputs from registers (slots tid+s*512; s>=4 are zero)
__device__ __forceinline__ void fwd8_first(float2* fb, int tt, const Tw& w, const float2* in){
    float2 b0 = in[0], b1 = in[1], b2 = in[2], b3 = in[3];
    float2 b4 = cmulf(in[0], w.w1);
    float2 b5 = cmulf(in[1], w.c1);
    float2 b6 = mulnegi(cmulf(in[2], w.w1));
    float2 b7 = cmulf(in[3], w.c3);
    float2 c0 = cadd(b0,b2), c2 = cmulf(csub(b0,b2), w.w2);
    float2 c1 = cadd(b1,b3), c3 = mulnegi(cmulf(csub(b1,b3), w.w2));
    float2 c4 = cadd(b4,b6), c6 = cmulf(csub(b4,b6), w.w2);
    float2 c5 = cadd(b5,b7), c7 = mulnegi(cmulf(csub(b5,b7), w.w2));
    fb[PHI(tt       )] = cadd(c0,c1);
    fb[PHI(tt +  512)] = cmulf(csub(c0,c1), w.w4);
    fb[PHI(tt + 1024)] = cadd(c2,c3);
    fb[PHI(tt + 1536)] = cmulf(csub(c2,c3), w.w4);
    fb[PHI(tt + 2048)] = cadd(c4,c5);
    fb[PHI(tt + 2560)] = cmulf(csub(c4,c5), w.w4);
    fb[PHI(tt + 3072)] = cadd(c6,c7);
    fb[PHI(tt + 3584)] = cmulf(csub(c6,c7), w.w4);
}

// inverse stage-9 triple returning only slots tid+s*512 (s=0..3) in registers
__device__ __forceinline__ void inv8_last(const float2* fb, int tt, const Tw& w, float2* outv){
    float2 u1 = cconj(w.w1), u2 = cconj(w.w2), u4 = cconj(w.w4);
    float2 uc1 = cconj(w.c1), uc3 = cconj(w.c3);
    float2 a0 = fb[PHI(tt       )], a1 = fb[PHI(tt +  512)];
    float2 a2 = fb[PHI(tt + 1024)], a3 = fb[PHI(tt + 1536)];
    float2 a4 = fb[PHI(tt + 2048)], a5 = fb[PHI(tt + 2560)];
    float2 a6 = fb[PHI(tt + 3072)], a7 = fb[PHI(tt + 3584)];
    float2 m;
    m = cmulf(a1, u4); float2 t0 = cadd(a0,m), t1 = csub(a0,m);
    m = cmulf(a3, u4); float2 t2 = cadd(a2,m), t3 = csub(a2,m);
    m = cmulf(a5, u4); float2 t4 = cadd(a4,m), t5 = csub(a4,m);
    m = cmulf(a7, u4); float2 t6 = cadd(a6,m), t7 = csub(a6,m);
    m = cmulf(t2, u2);          float2 e0 = cadd(t0,m), e2 = csub(t0,m);
    m = mulposi(cmulf(t3, u2)); float2 e1 = cadd(t1,m), e3 = csub(t1,m);
    m = cmulf(t6, u2);          float2 e4 = cadd(t4,m), e6 = csub(t4,m);
    m = mulposi(cmulf(t7, u2)); float2 e5 = cadd(t5,m), e7 = csub(t5,m);
    outv[0] = cadd(e0, cmulf(e4, u1));
    outv[1] = cadd(e1, cmulf(e5, uc1));
    outv[2] = cadd(e2, mulposi(cmulf(e6, u1)));
    outv[3] = cadd(e3, cmulf(e7, uc3));
}

// fused middle: fwd triple S=2 (identity tw) + pointwise*g + inv triple S=0,
// entirely in registers; reads/writes contiguous slots 8*tt..8*tt+7
__device__ __forceinline__ void mid8(float2* fb, int tt, const float2* g){
    const float R = 0.70710678118654752f;
    const int base = tt << 3;
    float2 a0 = fb[PHI(base  )], a1 = fb[PHI(base+1)];
    float2 a2 = fb[PHI(base+2)], a3 = fb[PHI(base+3)];
    float2 a4 = fb[PHI(base+4)], a5 = fb[PHI(base+5)];
    float2 a6 = fb[PHI(base+6)], a7 = fb[PHI(base+7)];
    // fwd S=2 triple (w1=w2=w4=1)
    float2 b0 = cadd(a0,a4), b1 = cadd(a1,a5), b2 = cadd(a2,a6), b3 = cadd(a3,a7);
    float2 b4 = csub(a0,a4);
    float2 b5 = cmulf(csub(a1,a5), make_float2( R, -R));
    float2 b6 = mulnegi(csub(a2,a6));
    float2 b7 = cmulf(csub(a3,a7), make_float2(-R, -R));
    float2 c0 = cadd(b0,b2), c2 = csub(b0,b2);
    float2 c1 = cadd(b1,b3), c3 = mulnegi(csub(b1,b3));
    float2 c4 = cadd(b4,b6), c6 = csub(b4,b6);
    float2 c5 = cadd(b5,b7), c7 = mulnegi(csub(b5,b7));
    float2 d0 = cadd(c0,c1), d1 = csub(c0,c1);
    float2 d2 = cadd(c2,c3), d3 = csub(c2,c3);
    float2 d4 = cadd(c4,c5), d5 = csub(c4,c5);
    float2 d6 = cadd(c6,c7), d7 = csub(c6,c7);
    // pointwise with G (g[k] = G at slot 8*tt+k)
    d0 = cmulf(d0, g[0]); d1 = cmulf(d1, g[1]); d2 = cmulf(d2, g[2]); d3 = cmulf(d3, g[3]);
    d4 = cmulf(d4, g[4]); d5 = cmulf(d5, g[5]); d6 = cmulf(d6, g[6]); d7 = cmulf(d7, g[7]);
    // inv S=0 triple (u1=u2=u4=1)
    float2 m;
    m = d1; float2 t0 = cadd(d0,m), t1 = csub(d0,m);
    m = d3; float2 t2 = cadd(d2,m), t3 = csub(d2,m);
    m = d5; float2 t4 = cadd(d4,m), t5 = csub(d4,m);
    m = d7; float2 t6 = cadd(d6,m), t7 = csub(d6,m);
    m = t2;          float2 e0 = cadd(t0,m), e2 = csub(t0,m);
    m = mulposi(t3); float2 e1 = cadd(t1,m), e3 = csub(t1,m);
    m = t6;          float2 e4 = cadd(t4,m), e6 = csub(t4,m);
    m = mulposi(t7); float2 e5 = cadd(t5,m), e7 = csub(t5,m);
    m = e4;                           fb[PHI(base  )] = cadd(e0,m); fb[PHI(base+4)] = csub(e0,m);
    m = cmulf(e5, make_float2(R, R)); fb[PHI(base+1)] = cadd(e1,m); fb[PHI(base+5)] = csub(e1,m);
    m = mulposi(e6);                  fb[PHI(base+2)] = cadd(e2,m); fb[PHI(base+6)] = csub(e2,m);
    m = cmulf(e7, make_float2(-R, R));fb[PHI(base+3)] = cadd(e3,m); fb[PHI(base+7)] = csub(e3,m);
}

// fwd S=2 triple with register outputs only (for G spectrum capture)
__device__ __forceinline__ void fwd8_last_reg(const float2* fb, int tt, float2* gout){
    const float R = 0.70710678118654752f;
    const int base = tt << 3;
    float2 a0 = fb[PHI(base  )], a1 = fb[PHI(base+1)];
    float2 a2 = fb[PHI(base+2)], a3 = fb[PHI(base+3)];
    float2 a4 = fb[PHI(base+4)], a5 = fb[PHI(base+5)];
    float2 a6 = fb[PHI(base+6)], a7 = fb[PHI(base+7)];
    float2 b0 = cadd(a0,a4), b1 = cadd(a1,a5), b2 = cadd(a2,a6), b3 = cadd(a3,a7);
    float2 b4 = csub(a0,a4);
    float2 b5 = cmulf(csub(a1,a5), make_float2( R, -R));
    float2 b6 = mulnegi(csub(a2,a6));
    float2 b7 = cmulf(csub(a3,a7), make_float2(-R, -R));
    float2 c0 = cadd(b0,b2), c2 = csub(b0,b2);
    float2 c1 = cadd(b1,b3), c3 = mulnegi(csub(b1,b3));
    float2 c4 = cadd(b4,b6), c6 = csub(b4,b6);
    float2 c5 = cadd(b5,b7), c7 = mulnegi(csub(b5,b7));
    gout[0] = cadd(c0,c1); gout[1] = csub(c0,c1);
    gout[2] = cadd(c2,c3); gout[3] = csub(c2,c3);
    gout[4] = cadd(c4,c5); gout[5] = csub(c4,c5);
    gout[6] = cadd(c6,c7); gout[7] = csub(c6,c7);
}

// circular convolution; result scaled by 4096
__device__ __forceinline__ void conv_fft(float2* fb, const float2* g, int tid,
                                         const Tw& T11, const Tw& T8, const Tw& T5,
                                         const float2* in, float2* outv){
    __syncthreads();                       // prior reads of fb done
    fwd8_first(fb, tid, T11, in); __syncthreads();
    fwd8c<8>(fb, tid, T8); __syncthreads();
    fwd8c<5>(fb, tid, T5); __syncthreads();
    mid8(fb, tid, g);      __syncthreads();
    inv8c<3>(fb, tid, T5); __syncthreads();
    inv8c<6>(fb, tid, T8); __syncthreads();
    inv8_last(fb, tid, T11, outv);
}

// ---------------- block reductions (512 threads = 8 waves), result to all
__device__ float block_reduce8(float v, volatile float* sc) {
    int lane = threadIdx.x & 63, wid = threadIdx.x >> 6;
    #pragma unroll
    for (int off = 32; off > 0; off >>= 1) v += __shfl_down(v, off, 64);
    if (lane == 0) sc[wid] = v;
    __syncthreads();
    if (wid == 0) {
        float s = (lane < 8) ? sc[lane] : 0.0f;
        #pragma unroll
        for (int off = 4; off > 0; off >>= 1) s += __shfl_down(s, off, 64);
        if (lane == 0) sc[16] = s;
    }
    __syncthreads();
    return sc[16];
}

__device__ float2 block_reduce2(float2 v, volatile float* sc) {
    int lane = threadIdx.x & 63, wid = threadIdx.x >> 6;
    #pragma unroll
    for (int off = 32; off > 0; off >>= 1) {
        v.x += __shfl_down(v.x, off, 64);
        v.y += __shfl_down(v.y, off, 64);
    }
    if (lane == 0) { sc[wid] = v.x; sc[17 + wid] = v.y; }
    __syncthreads();
    if (wid == 0) {
        float sx = (lane < 8) ? sc[lane] : 0.0f;
        float sy = (lane < 8) ? sc[17 + lane] : 0.0f;
        #pragma unroll
        for (int off = 4; off > 0; off >>= 1) {
            sx += __shfl_down(sx, off, 64);
            sy += __shfl_down(sy, off, 64);
        }
        if (lane == 0) { sc[16] = sx; sc[33] = sy; }
    }
    __syncthreads();
    return make_float2(sc[16], sc[33]);
}

// ======================= the cooperative mega-kernel =======================
__global__ __launch_bounds__(512) __attribute__((amdgpu_waves_per_eu(2, 2)))
void mega(const float* __restrict__ x, const float* __restrict__ y,
          const float* __restrict__ xn, const float* __restrict__ z,
          float* __restrict__ out,
          float2* __restrict__ d_v, float2* __restrict__ d_rhs, float2* __restrict__ d_wb,
          float* __restrict__ d_al, float* __restrict__ d_be, float* __restrict__ d_nz2,
          float* __restrict__ d_quad, float* __restrict__ d_t1p)
{
    __shared__ float2 fb[FBN];
    __shared__ float  redb[40];
    cg::grid_group grid = cg::this_grid();
    const int b = blockIdx.x, tid = threadIdx.x;
    const int wid = tid >> 6, lane = tid & 63;

    // ---------------- phase P: build v (3073 cols) and rhs (1537 cols), one wave per col
    for (int c = b*8 + wid; c < 3073 + MN; c += 2048) {
        bool is_v = c < 3073;
        float pk = is_v ? (float)(c - 1536) : (float)(c - 3073 - 768);
        float sx = 0.f, sy = 0.f;
        if (is_v){
            for (int j = 0; j < 256; ++j){
                float ph = CW * (x[j*64 + lane] * pk);
                float s, cc; __sincosf(ph, &s, &cc);
                sx += cc; sy += s;
            }
        } else {
            for (int j = 0; j < 256; ++j){
                int n = j*64 + lane;
                float yv = y[n];
                float ph = CW * (x[n] * pk);
                float s, cc; __sincosf(ph, &s, &cc);
                sx += cc*yv; sy -= s*yv;
            }
        }
        #pragma unroll
        for (int off = 32; off > 0; off >>= 1){
            sx += __shfl_down(sx, off, 64);
            sy += __shfl_down(sy, off, 64);
        }
        if (lane == 0){
            if (is_v) d_v[c] = make_float2(sx, sy);
            else      d_rhs[c - 3073] = make_float2(sx, sy);
        }
    }
    grid.sync();

    // ---------------- phase S: blocks 0..63 Lanczos, block 64 CG
    if (b < 65) {
        Tw T11 = make_tw(-W4096 * (float)tid);
        Tw T8  = make_tw(-W4096 * (float)((tid & 63) << 3));
        Tw T5  = make_tw(-W4096 * (float)((tid & 7)  << 6));
        bool on3 = (tid == 0);
        float w[4];
        w[0] = ws_at(tid); w[1] = ws_at(tid + 512); w[2] = ws_at(tid + 1024);
        w[3] = on3 ? ws_at(1536) : 0.f;

        // build G spectrum into registers g[k] = G[8*tid + k]
        float2 g[8];
        #pragma unroll
        for (int k = 0; k < 8; ++k){
            int i = tid + k*512;
            float2 val = make_float2(0.f, 0.f);
            if (i == 0)            val = d_v[1536];
            else if (i <= 1536)    val = d_v[1536 - i];
            else if (i >= 2560)    val = d_v[5632 - i];
            fb[PHI(i)] = val;
        }
        __syncthreads();
        fwd8c<11>(fb, tid, T11); __syncthreads();
        fwd8c<8 >(fb, tid, T8);  __syncthreads();
        fwd8c<5 >(fb, tid, T5);  __syncthreads();
        fwd8_last_reg(fb, tid, g);

        float2 sin_[4], cv[4];
        if (b < 64) {
            // ---------- Lanczos (fused dual reduction: beta^2 = |v|^2 - alpha^2)
            float2 q[4], qp[4];
            float part = 0.f;
            #pragma unroll
            for (int s = 0; s < 4; ++s){
                float sv = 0.f;
                if (s < 3 || on3){
                    float zv = z[b*MN + tid + s*512];
                    sv = (zv > 0.f) ? 1.f : ((zv < 0.f) ? -1.f : 0.f);
                }
                q[s] = make_float2(sv, 0.f);
                qp[s] = make_float2(0.f, 0.f);
                part += sv * sv;
            }
            float nz2 = block_reduce8(part, redb);
            if (tid == 0) d_nz2[b] = nz2;
            float qs = 1.0f / sqrtf(nz2);
            #pragma unroll
            for (int s = 0; s < 4; ++s){ q[s].x *= qs; q[s].y *= qs; }
            float bp = 0.f;
            float cf[4];
            #pragma unroll
            for (int s = 0; s < 4; ++s) cf[s] = w[s] * (10.0f / 4096.0f);
            for (int step = 0; step < 50; ++step) {
                #pragma unroll
                for (int s = 0; s < 4; ++s)
                    sin_[s] = make_float2(w[s]*q[s].x, w[s]*q[s].y);
                conv_fft(fb, g, tid, T11, T8, T5, sin_, cv);
                float2 v[4];
                float2 pp = make_float2(0.f, 0.f);   // (q.v, v.v)
                #pragma unroll
                for (int s = 0; s < 4; ++s){
                    v[s] = make_float2(q[s].x + cf[s]*cv[s].x - bp*qp[s].x,
                                       q[s].y + cf[s]*cv[s].y - bp*qp[s].y);
                    pp.x += q[s].x*v[s].x + q[s].y*v[s].y;
                    pp.y += v[s].x*v[s].x + v[s].y*v[s].y;
                }
                float2 rr = block_reduce2(pp, redb);
                float alpha = rr.x;
                float beta = sqrtf(fmaxf(rr.y - alpha*alpha, 0.f));
                if (tid == 0) { d_al[b*50 + step] = alpha; d_be[b*50 + step] = beta; }
                float binv = 1.0f / fmaxf(beta, 1e-12f);
                #pragma unroll
                for (int s = 0; s < 4; ++s){
                    float2 nq = make_float2((v[s].x - alpha*q[s].x)*binv,
                                            (v[s].y - alpha*q[s].y)*binv);
                    qp[s] = q[s];
                    q[s] = nq;
                }
                bp = beta;
            }
        } else {
            // ---------- CG (classic two reductions; off critical path)
            float2 r[4], p[4], xx[4];
            float part = 0.f;
            #pragma unroll
            for (int s = 0; s < 4; ++s){
                float2 bj = make_float2(0.f, 0.f);
                if (s < 3 || on3){
                    float2 rv = d_rhs[tid + s*512];
                    bj = make_float2(w[s]*rv.x, w[s]*rv.y);
                }
                r[s] = bj; p[s] = bj; xx[s] = make_float2(0.f, 0.f);
                part += bj.x*bj.x + bj.y*bj.y;
            }
            float rs = block_reduce8(part, redb);
            float cf[4];
            #pragma unroll
            for (int s = 0; s < 4; ++s) cf[s] = w[s] * (1.0f / 4096.0f);
            for (int it = 0; it < 50; ++it) {
                #pragma unroll
                for (int s = 0; s < 4; ++s)
                    sin_[s] = make_float2(w[s]*p[s].x, w[s]*p[s].y);
                conv_fft(fb, g, tid, T11, T8, T5, sin_, cv);
                float2 ap[4];
                part = 0.f;
                #pragma unroll
                for (int s = 0; s < 4; ++s){
                    ap[s] = make_float2(cf[s]*cv[s].x + 0.1f*p[s].x,
                                        cf[s]*cv[s].y + 0.1f*p[s].y);
                    part += p[s].x*ap[s].x + p[s].y*ap[s].y;
                }
                float pAp = block_reduce8(part, redb);
                float a = rs / pAp;
                part = 0.f;
                #pragma unroll
                for (int s = 0; s < 4; ++s){
                    xx[s].x += a*p[s].x; xx[s].y += a*p[s].y;
                    r[s].x -= a*ap[s].x; r[s].y -= a*ap[s].y;
                    part += r[s].x*r[s].x + r[s].y*r[s].y;
                }
                float rsn = block_reduce8(part, redb);
                float sc = rsn / rs;
                #pragma unroll
                for (int s = 0; s < 4; ++s)
                    p[s] = make_float2(r[s].x + sc*p[s].x, r[s].y + sc*p[s].y);
                rs = rsn;
            }
            #pragma unroll
            for (int s = 0; s < 4; ++s){
                if (s < 3 || on3)
                    d_wb[tid + s*512] = make_float2(w[s]*xx[s].x, w[s]*xx[s].y);
            }
        }
    }
    grid.sync();

    // ---------------- phase T: slq (blocks 0-63) | mean (64-95) | t1 (96-223)
    if (b < 64) {
        if (tid < 64) {
            float* sa  = (float*)fb;       // a[64] | e[64] | e2[64]
            float* se  = sa + 64;
            float* se2 = sa + 128;
            int t = tid;
            if (t < 50) {
                sa[t] = d_al[b*50 + t];
                float bv = (t < 49) ? d_be[b*50 + t] : 0.0f;
                se[t] = bv; se2[t] = bv * bv;
            }
            float quad = 0.0f;
            if (t < 50) {
                float lo = 3.4e38f, hi = -3.4e38f;
                for (int i = 0; i < 50; ++i) {
                    float rr = ((i > 0) ? fabsf(se[i-1]) : 0.0f) + ((i < 49) ? fabsf(se[i]) : 0.0f);
                    lo = fminf(lo, sa[i] - rr);
                    hi = fmaxf(hi, sa[i] + rr);
                }
                for (int it = 0; it < 38; ++it) {
                    float mid = 0.5f * (lo + hi);
                    int cnt = 0;
                    float qq = sa[0] - mid;
                    cnt += (qq < 0.0f);
                    for (int k = 1; k < 50; ++k) {
                        float dnm = (fabsf(qq) < 1e-30f) ? ((qq < 0.0f) ? -1e-30f : 1e-30f) : qq;
                        qq = (sa[k] - mid) - se2[k-1] * __builtin_amdgcn_rcpf(dnm);
                        cnt += (qq < 0.0f);
                    }
                    if (cnt > t) hi = mid; else lo = mid;
                }
                float lam = 0.5f * (lo + hi);
                float pm = 0.0f, pc = 1.0f, s = 1.0f, bprev = 0.0f;
                for (int k = 0; k < 49; ++k) {
                    float bk = fmaxf(se[k], 1e-30f);
                    float pn = ((lam - sa[k]) * pc - bprev * pm) * __builtin_amdgcn_rcpf(bk);
                    pn = fminf(fmaxf(pn, -1e18f), 1e18f);
                    s += pn * pn;
                    pm = pc; pc = pn; bprev = bk;
                }
                quad = logf(fmaxf(lam, 1e-18f)) / s;
            }
            #pragma unroll
            for (int off = 32; off > 0; off >>= 1) quad += __shfl_down(quad, off, 64);
            if (t == 0) d_quad[b] = quad * d_nz2[b];
        }
    } else if (b < 96) {
        int row = (b - 64)*128 + (tid >> 2);
        int sub = tid & 3;
        float xv = xn[row];
        float acc = 0.f;
        for (int k = sub; k < MN; k += 4) {
            float ph = CW * (xv * (float)(k - 768));
            float s, c; __sincosf(ph, &s, &c);
            float2 ww = d_wb[k];
            acc += c * ww.x - s * ww.y;
        }
        acc += __shfl_down(acc, 2, 4);
        acc += __shfl_down(acc, 1, 4);
        if (sub == 0) out[row] = acc;
    } else if (b < 224) {
        int n = (b - 96)*128 + (tid >> 2);
        int sub = tid & 3;
        float xv = x[n], yv = y[n];
        float acc = 0.f;
        for (int k = sub; k < MN; k += 4) {
            float ph = CW * (xv * (float)(k - 768));
            float s, c; __sincosf(ph, &s, &c);
            float2 ww = d_wb[k];
            acc += c * ww.x - s * ww.y;
        }
        acc += __shfl_down(acc, 2, 4);
        acc += __shfl_down(acc, 1, 4);
        float contrib = (sub == 0) ? yv * (yv - acc) * 10.0f : 0.f;
        #pragma unroll
        for (int off = 32; off > 0; off >>= 1) contrib += __shfl_down(contrib, off, 64);
        if (lane == 0) redb[wid] = contrib;
        __syncthreads();
        if (tid == 0) {
            float s = 0.f;
            #pragma unroll
            for (int i = 0; i < 8; ++i) s += redb[i];
            d_t1p[b - 96] = s;
        }
    }
    grid.sync();

    // ---------------- final: lml
    if (b == 0 && tid < 64) {
        float qv = d_quad[tid];
        float t1 = d_t1p[tid] + d_t1p[tid + 64];
        #pragma unroll
        for (int off = 32; off > 0; off >>= 1) {
            qv += __shfl_down(qv, off, 64);
            t1 += __shfl_down(t1, off, 64);
        }
        if (tid == 0) {
            float ld = qv / 64.0f - 37725.5542f;              // + N*log(sigma^2)
            out[4096] = -0.5f * t1 - 0.5f * ld - 15055.8889f; // - 0.5*N*log(2pi)
        }
    }
}

extern "C" void kernel_launch(void* const* d_in, const int* in_sizes, int n_in,
                              void* d_out, int out_size, void* d_ws, size_t ws_size,
                              hipStream_t stream) {
    const float* d_x  = (const float*)d_in[0];
    const float* d_y  = (const float*)d_in[1];
    const float* d_xn = (const float*)d_in[2];
    const float* d_z  = (const float*)d_in[3];
    float* out = (float*)d_out;
    char* w = (char*)d_ws;
    float2* d_v   = (float2*)(w + 0);       // 3073 c64
    float2* d_rhs = (float2*)(w + 24832);   // 1537 c64
    float2* d_wb  = (float2*)(w + 37376);   // 1537 c64
    float*  d_al  = (float*)(w + 49920);    // 64x50
    float*  d_be  = (float*)(w + 62720);    // 64x50
    float*  d_nz2 = (float*)(w + 75520);    // 64
    float*  d_quad= (float*)(w + 75776);    // 64
    float*  d_t1p = (float*)(w + 76032);    // 128

    void* args[] = { (void*)&d_x, (void*)&d_y, (void*)&d_xn, (void*)&d_z, (void*)&out,
                     (void*)&d_v, (void*)&d_rhs, (void*)&d_wb, (void*)&d_al, (void*)&d_be,
                     (void*)&d_nz2, (void*)&d_quad, (void*)&d_t1p };
    hipLaunchCooperativeKernel((const void*)mega, dim3(256), dim3(512), args, 0, stream);
}